// Round 1
// baseline (2040.779 us; speedup 1.0000x reference)
//
#include <hip/hip_runtime.h>
#include <hip/hip_bf16.h>

// Problem constants (fixed by setup_inputs): B=4, N=1024, C=1152, H=16, hd=72
#define PB 4
#define PN 1024
#define PC 1152
#define PH 16
#define PHD 72
#define BH (PB*PH)              // 64
#define QKV_COLS (3*PC)         // 3456
#define OUT_ELEMS ((size_t)PB*PN*PC)   // 4718592
#define AT_STRIDE 76            // padded LDS stride for 72-dim rows

// ---------------------------------------------------------------------------
// QKV GEMM: qkv[m, c] = sum_k x[m,k] * qkv_w[c,k] + qkv_b[c]
// scatter to q/k/v in (BH, N, hd) layout; q pre-scaled by hd^-0.5
// ---------------------------------------------------------------------------
__global__ __launch_bounds__(256) void gemm_qkv(
    const float* __restrict__ x, const float* __restrict__ w,
    const float* __restrict__ bias,
    float* __restrict__ q, float* __restrict__ k, float* __restrict__ v)
{
    const int t  = threadIdx.x;
    const int tx = t & 15, ty = t >> 4;
    const int c0 = blockIdx.x * 64;
    const int m0 = blockIdx.y * 64;
    const int K = PC;

    __shared__ float As[64 * 36];
    __shared__ float Bs[64 * 36];

    float acc[4][4];
#pragma unroll
    for (int i = 0; i < 4; ++i)
#pragma unroll
        for (int j = 0; j < 4; ++j) acc[i][j] = 0.f;

    for (int kt = 0; kt < K; kt += 32) {
#pragma unroll
        for (int i = 0; i < 2; ++i) {
            int id = t + i * 256;
            int row = id >> 3, kk4 = (id & 7) * 4;
            *(float4*)&As[row * 36 + kk4] =
                *(const float4*)&x[(size_t)(m0 + row) * K + kt + kk4];
            *(float4*)&Bs[row * 36 + kk4] =
                *(const float4*)&w[(size_t)(c0 + row) * K + kt + kk4];
        }
        __syncthreads();
#pragma unroll
        for (int kk = 0; kk < 32; kk += 4) {
            float4 a[4], bb[4];
#pragma unroll
            for (int i = 0; i < 4; ++i) a[i]  = *(const float4*)&As[(ty + i * 16) * 36 + kk];
#pragma unroll
            for (int j = 0; j < 4; ++j) bb[j] = *(const float4*)&Bs[(tx + j * 16) * 36 + kk];
#pragma unroll
            for (int i = 0; i < 4; ++i)
#pragma unroll
                for (int j = 0; j < 4; ++j)
                    acc[i][j] += a[i].x * bb[j].x + a[i].y * bb[j].y
                               + a[i].z * bb[j].z + a[i].w * bb[j].w;
        }
        __syncthreads();
    }

    const float scale = 0.11785113019775792f; // 72^-0.5
#pragma unroll
    for (int i = 0; i < 4; ++i) {
        int m = m0 + ty + i * 16;
        int b = m >> 10, n = m & 1023;
#pragma unroll
        for (int j = 0; j < 4; ++j) {
            int c = c0 + tx + j * 16;
            float val = acc[i][j] + bias[c];
            int jq  = c / PC;
            int rem = c - jq * PC;
            int h = rem / PHD, d = rem - h * PHD;
            size_t dst = (((size_t)(b * PH + h)) * PN + n) * PHD + d;
            if (jq == 0)      q[dst] = val * scale;
            else if (jq == 1) k[dst] = val;
            else              v[dst] = val;
        }
    }
}

// ---------------------------------------------------------------------------
// Flash attention per (bh, 64-row Q tile). 256 threads = 64 rows x 4 slots.
// Q pre-scaled. enc_mode: accumulate (xout - o_star)^2 into loss_accum.
// ---------------------------------------------------------------------------
__global__ __launch_bounds__(256) void attn_kernel(
    const float* __restrict__ qbase, const float* __restrict__ kbase,
    const float* __restrict__ vbase, float* __restrict__ outbase,
    const float* __restrict__ xout_for_loss, float* __restrict__ loss_accum,
    int enc_mode)
{
    const int bh = blockIdx.y;
    const int n0 = blockIdx.x * 64;
    const int t = threadIdx.x;
    const int r = t >> 2;   // row within tile, 0..63
    const int s = t & 3;    // slot 0..3 (owns output dims s*18 .. s*18+17)

    __shared__ float Qs[64 * AT_STRIDE];
    __shared__ float Ks[64 * AT_STRIDE];
    __shared__ float Vs[64 * AT_STRIDE];
    __shared__ float Ps[64 * 65];
    __shared__ float redmax[64 * 4];
    __shared__ float redsum[64 * 4];

    const float* qp = qbase + (size_t)bh * PN * PHD + (size_t)n0 * PHD;
    const float* kp = kbase + (size_t)bh * PN * PHD;
    const float* vp = vbase + (size_t)bh * PN * PHD;

    // load Q tile (64 x 72) as float4s
    for (int idx = t; idx < 64 * 18; idx += 256) {
        int row = idx / 18, d4 = idx % 18;
        *(float4*)(&Qs[row * AT_STRIDE + d4 * 4]) =
            *(const float4*)(qp + row * PHD + d4 * 4);
    }

    float O[18];
#pragma unroll
    for (int i = 0; i < 18; ++i) O[i] = 0.f;
    float m_run = -1e30f, l_run = 0.f;

    for (int kt = 0; kt < 16; ++kt) {
        __syncthreads();  // protect Ks/Vs/Ps (covers initial Q load too)
        for (int idx = t; idx < 64 * 18; idx += 256) {
            int row = idx / 18, d4 = idx % 18;
            *(float4*)(&Ks[row * AT_STRIDE + d4 * 4]) =
                *(const float4*)(kp + (size_t)kt * 64 * PHD + row * PHD + d4 * 4);
            *(float4*)(&Vs[row * AT_STRIDE + d4 * 4]) =
                *(const float4*)(vp + (size_t)kt * 64 * PHD + row * PHD + d4 * 4);
        }
        __syncthreads();

        // S: this thread computes keys j = 4*jj + s
        float sc[16];
#pragma unroll
        for (int jj = 0; jj < 16; ++jj) sc[jj] = 0.f;
        for (int d4 = 0; d4 < 18; ++d4) {
            float4 q4 = *(const float4*)(&Qs[r * AT_STRIDE + d4 * 4]);
#pragma unroll
            for (int jj = 0; jj < 16; ++jj) {
                int j = jj * 4 + s;
                float4 k4 = *(const float4*)(&Ks[j * AT_STRIDE + d4 * 4]);
                sc[jj] += q4.x * k4.x + q4.y * k4.y + q4.z * k4.z + q4.w * k4.w;
            }
        }

        float lmax = sc[0];
#pragma unroll
        for (int jj = 1; jj < 16; ++jj) lmax = fmaxf(lmax, sc[jj]);
        redmax[r * 4 + s] = lmax;
        __syncthreads();

        float tile_max = fmaxf(fmaxf(redmax[r * 4 + 0], redmax[r * 4 + 1]),
                               fmaxf(redmax[r * 4 + 2], redmax[r * 4 + 3]));
        float m_new = fmaxf(m_run, tile_max);
        float lsum = 0.f;
#pragma unroll
        for (int jj = 0; jj < 16; ++jj) {
            float p = __expf(sc[jj] - m_new);
            Ps[r * 65 + jj * 4 + s] = p;
            lsum += p;
        }
        redsum[r * 4 + s] = lsum;
        float alpha = __expf(m_run - m_new);
        m_run = m_new;
        __syncthreads();

        float tile_sum = redsum[r * 4 + 0] + redsum[r * 4 + 1]
                       + redsum[r * 4 + 2] + redsum[r * 4 + 3];
        l_run = l_run * alpha + tile_sum;
#pragma unroll
        for (int i = 0; i < 18; ++i) O[i] *= alpha;

        const int dbase = s * 18;
        for (int j = 0; j < 64; ++j) {
            float pj = Ps[r * 65 + j];
#pragma unroll
            for (int i2 = 0; i2 < 9; ++i2) {
                float2 v2 = *(const float2*)(&Vs[j * AT_STRIDE + dbase + i2 * 2]);
                O[i2 * 2]     += pj * v2.x;
                O[i2 * 2 + 1] += pj * v2.y;
            }
        }
    }

    float inv_l = 1.0f / l_run;
    int b = bh >> 4, h = bh & 15;
    size_t dst = ((size_t)(b * PN + n0 + r)) * PC + h * PHD + s * 18;

    if (!enc_mode) {
#pragma unroll
        for (int i = 0; i < 18; ++i) outbase[dst + i] = O[i] * inv_l;
    } else {
        float lacc = 0.f;
#pragma unroll
        for (int i = 0; i < 18; ++i) {
            float o = O[i] * inv_l;
            float d = xout_for_loss[dst + i] - o;
            lacc += d * d;
        }
        __syncthreads();          // redsum last read in loop above
        redsum[t] = lacc;
        __syncthreads();
        for (int off = 128; off > 0; off >>= 1) {
            if (t < off) redsum[t] += redsum[t + off];
            __syncthreads();
        }
        if (t == 0) atomicAdd(loss_accum, redsum[0]);
    }
}

// ---------------------------------------------------------------------------
// Proj GEMM: out[m, c] = sum_k xout[m,k] * proj_w[c,k] + proj_b[c]
// ---------------------------------------------------------------------------
__global__ __launch_bounds__(256) void gemm_proj(
    const float* __restrict__ xo, const float* __restrict__ w,
    const float* __restrict__ bias, float* __restrict__ out)
{
    const int t  = threadIdx.x;
    const int tx = t & 15, ty = t >> 4;
    const int c0 = blockIdx.x * 64;
    const int m0 = blockIdx.y * 64;
    const int K = PC;

    __shared__ float As[64 * 36];
    __shared__ float Bs[64 * 36];

    float acc[4][4];
#pragma unroll
    for (int i = 0; i < 4; ++i)
#pragma unroll
        for (int j = 0; j < 4; ++j) acc[i][j] = 0.f;

    for (int kt = 0; kt < K; kt += 32) {
#pragma unroll
        for (int i = 0; i < 2; ++i) {
            int id = t + i * 256;
            int row = id >> 3, kk4 = (id & 7) * 4;
            *(float4*)&As[row * 36 + kk4] =
                *(const float4*)&xo[(size_t)(m0 + row) * K + kt + kk4];
            *(float4*)&Bs[row * 36 + kk4] =
                *(const float4*)&w[(size_t)(c0 + row) * K + kt + kk4];
        }
        __syncthreads();
#pragma unroll
        for (int kk = 0; kk < 32; kk += 4) {
            float4 a[4], bb[4];
#pragma unroll
            for (int i = 0; i < 4; ++i) a[i]  = *(const float4*)&As[(ty + i * 16) * 36 + kk];
#pragma unroll
            for (int j = 0; j < 4; ++j) bb[j] = *(const float4*)&Bs[(tx + j * 16) * 36 + kk];
#pragma unroll
            for (int i = 0; i < 4; ++i)
#pragma unroll
                for (int j = 0; j < 4; ++j)
                    acc[i][j] += a[i].x * bb[j].x + a[i].y * bb[j].y
                               + a[i].z * bb[j].z + a[i].w * bb[j].w;
        }
        __syncthreads();
    }

#pragma unroll
    for (int i = 0; i < 4; ++i) {
        int m = m0 + ty + i * 16;
#pragma unroll
        for (int j = 0; j < 4; ++j) {
            int c = c0 + tx + j * 16;
            out[(size_t)m * PC + c] = acc[i][j] + bias[c];
        }
    }
}

__global__ void finalize_loss(const float* __restrict__ accum, float* __restrict__ dst)
{
    if (threadIdx.x == 0) dst[0] = accum[0] * (1.0f / (float)OUT_ELEMS);
}

// ---------------------------------------------------------------------------
extern "C" void kernel_launch(void* const* d_in, const int* in_sizes, int n_in,
                              void* d_out, int out_size, void* d_ws, size_t ws_size,
                              hipStream_t stream)
{
    const float* x      = (const float*)d_in[0];
    const float* enc_k  = (const float*)d_in[1];
    const float* enc_v  = (const float*)d_in[2];
    const float* qkv_w  = (const float*)d_in[3];
    const float* qkv_b  = (const float*)d_in[4];
    const float* proj_w = (const float*)d_in[5];
    const float* proj_b = (const float*)d_in[6];
    // d_in[7] = stage (fixed at 2)

    float* out = (float*)d_out;
    float* ws  = (float*)d_ws;

    float* q_ws     = ws;
    float* k_ws     = ws + OUT_ELEMS;
    float* v_ws     = ws + 2 * OUT_ELEMS;
    float* xout     = ws + 3 * OUT_ELEMS;
    float* loss_acc = ws + 4 * OUT_ELEMS;

    // 1. QKV projection, scatter to (BH, N, hd); q pre-scaled
    gemm_qkv<<<dim3(QKV_COLS / 64, (PB * PN) / 64), 256, 0, stream>>>(
        x, qkv_w, qkv_b, q_ws, k_ws, v_ws);

    // 2. Own-KV attention -> xout in (B, N, C) layout
    attn_kernel<<<dim3(PN / 64, BH), 256, 0, stream>>>(
        q_ws, k_ws, v_ws, xout, nullptr, nullptr, 0);

    // 3. Output projection (depends only on xout)
    gemm_proj<<<dim3(PC / 64, (PB * PN) / 64), 256, 0, stream>>>(
        xout, proj_w, proj_b, out);

    // 4. Encoder-KV attention + fused distill-loss accumulation
    hipMemsetAsync(loss_acc, 0, sizeof(float), stream);
    attn_kernel<<<dim3(PN / 64, BH), 256, 0, stream>>>(
        q_ws, enc_k, enc_v, nullptr, xout, loss_acc, 1);

    // 5. loss = accum / (B*H*N*hd)
    finalize_loss<<<1, 64, 0, stream>>>(loss_acc, out + OUT_ELEMS);
}

// Round 2
// 1395.472 us; speedup vs baseline: 1.4624x; 1.4624x over previous
//
#include <hip/hip_runtime.h>
#include <hip/hip_bf16.h>

// Problem constants (fixed by setup_inputs): B=4, N=1024, C=1152, H=16, hd=72
#define PB 4
#define PN 1024
#define PC 1152
#define PH 16
#define PHD 72
#define BH (PB*PH)              // 64
#define QKV_COLS (3*PC)         // 3456
#define OUT_ELEMS ((size_t)PB*PN*PC)   // 4718592
#define AT_STRIDE 76            // padded LDS stride for 72-dim rows
#define K_DIM 1152

typedef _Float16 half8_t __attribute__((ext_vector_type(8)));
typedef float float4v __attribute__((ext_vector_type(4)));

__device__ __forceinline__ void load16_lds(const _Float16* g, _Float16* l) {
    __builtin_amdgcn_global_load_lds(
        (const __attribute__((address_space(1))) void*)g,
        (__attribute__((address_space(3))) void*)l, 16, 0, 0);
}

// ---------------------------------------------------------------------------
// fp32 -> f16 conversion (memory-bound, trivial)
// ---------------------------------------------------------------------------
__global__ __launch_bounds__(256) void f32_to_f16(
    const float* __restrict__ in, _Float16* __restrict__ out, int n8)
{
    int i = blockIdx.x * 256 + threadIdx.x;
    if (i >= n8) return;
    float4 a = ((const float4*)in)[2 * i];
    float4 b = ((const float4*)in)[2 * i + 1];
    half8_t h;
    h[0] = (_Float16)a.x; h[1] = (_Float16)a.y; h[2] = (_Float16)a.z; h[3] = (_Float16)a.w;
    h[4] = (_Float16)b.x; h[5] = (_Float16)b.y; h[6] = (_Float16)b.z; h[7] = (_Float16)b.w;
    ((half8_t*)out)[i] = h;
}

// ---------------------------------------------------------------------------
// MFMA f16 GEMM, 128x128 tile, BK=64, m97-style global_load_lds staging.
// C[m,c] = sum_k A[m,k] * Bm[c,k]  (both row-major, K contiguous)
// MODE 0: QKV epilogue (bias + scatter to q/k/v in (BH,N,hd), q scaled)
// MODE 1: proj epilogue (bias + store (M,C) row-major)
// ---------------------------------------------------------------------------
template<int MODE>
__global__ __launch_bounds__(256) void gemm_mfma(
    const _Float16* __restrict__ A, const _Float16* __restrict__ Bm,
    const float* __restrict__ bias,
    float* __restrict__ q, float* __restrict__ k, float* __restrict__ v,
    float* __restrict__ out)
{
    const int t    = threadIdx.x;
    const int lane = t & 63;
    const int w    = t >> 6;
    const int wm   = w >> 1, wn = w & 1;
    const int lrow = lane & 15, quad = lane >> 4;
    const int m0   = blockIdx.y * 128;
    const int c0   = blockIdx.x * 128;

    // LDS layout: idx = (kt2*4 + q)*128 + row, 8 halves each.
    // DMA-contiguous for staging; fragment reads spread evenly over 32 banks.
    __shared__ _Float16 As[8192];
    __shared__ _Float16 Bs[8192];

    int rowS[4], koff[4], ldsOff[4];
#pragma unroll
    for (int i = 0; i < 4; ++i) {
        int idx = w * 256 + i * 64 + lane;
        int kt2 = idx >> 9, qq = (idx >> 7) & 3;
        rowS[i]   = idx & 127;
        koff[i]   = kt2 * 32 + qq * 8;
        ldsOff[i] = idx * 8;
    }

    const _Float16* aBase = A  + (size_t)m0 * K_DIM;
    const _Float16* bBase = Bm + (size_t)c0 * K_DIM;

    float4v acc[4][4];
#pragma unroll
    for (int ti = 0; ti < 4; ++ti)
#pragma unroll
        for (int tj = 0; tj < 4; ++tj)
            acc[ti][tj] = (float4v){0.f, 0.f, 0.f, 0.f};

    for (int kb = 0; kb < K_DIM; kb += 64) {
        __syncthreads();
#pragma unroll
        for (int i = 0; i < 4; ++i) {
            load16_lds(aBase + (size_t)rowS[i] * K_DIM + kb + koff[i], &As[ldsOff[i]]);
            load16_lds(bBase + (size_t)rowS[i] * K_DIM + kb + koff[i], &Bs[ldsOff[i]]);
        }
        __syncthreads();
#pragma unroll
        for (int s = 0; s < 2; ++s) {
            half8_t af[4], bf[4];
#pragma unroll
            for (int ti = 0; ti < 4; ++ti)
                af[ti] = *(const half8_t*)&As[(((s * 4 + quad) * 128) + wm * 64 + ti * 16 + lrow) * 8];
#pragma unroll
            for (int tj = 0; tj < 4; ++tj)
                bf[tj] = *(const half8_t*)&Bs[(((s * 4 + quad) * 128) + wn * 64 + tj * 16 + lrow) * 8];
#pragma unroll
            for (int ti = 0; ti < 4; ++ti)
#pragma unroll
                for (int tj = 0; tj < 4; ++tj)
                    acc[ti][tj] = __builtin_amdgcn_mfma_f32_16x16x32_f16(
                        af[ti], bf[tj], acc[ti][tj], 0, 0, 0);
        }
    }

    // Epilogue. C/D layout: col = lane&15, row = quad*4 + reg (m91-verified).
    if (MODE == 0) {
        const float scale = 0.11785113019775792f; // 72^-0.5
#pragma unroll
        for (int tj = 0; tj < 4; ++tj) {
            int c = c0 + wn * 64 + tj * 16 + lrow;
            float bv = bias[c];
            int jq  = c / PC;
            int rem = c - jq * PC;
            int h   = rem / PHD;
            int d   = rem - h * PHD;
            float mul = (jq == 0) ? scale : 1.f;
            float* dstp = (jq == 0) ? q : (jq == 1) ? k : v;
            size_t hoff = (size_t)h * (PN * PHD) + d;
#pragma unroll
            for (int ti = 0; ti < 4; ++ti)
#pragma unroll
                for (int r = 0; r < 4; ++r) {
                    int m = m0 + wm * 64 + ti * 16 + quad * 4 + r;
                    int b = m >> 10, n = m & 1023;
                    size_t dst = (size_t)b * (PH * PN * PHD) + hoff + (size_t)n * PHD;
                    dstp[dst] = (acc[ti][tj][r] + bv) * mul;
                }
        }
    } else {
#pragma unroll
        for (int tj = 0; tj < 4; ++tj) {
            int c = c0 + wn * 64 + tj * 16 + lrow;
            float bv = bias[c];
#pragma unroll
            for (int ti = 0; ti < 4; ++ti)
#pragma unroll
                for (int r = 0; r < 4; ++r) {
                    int m = m0 + wm * 64 + ti * 16 + quad * 4 + r;
                    out[(size_t)m * PC + c] = acc[ti][tj][r] + bv;
                }
        }
    }
}

// ---------------------------------------------------------------------------
// Flash attention per (bh, 64-row Q tile). 256 threads = 64 rows x 4 slots.
// Q pre-scaled. enc_mode: accumulate (xout - o_star)^2 into loss_accum.
// !enc_mode additionally writes f16 copy of xout for the proj MFMA GEMM.
// ---------------------------------------------------------------------------
__global__ __launch_bounds__(256) void attn_kernel(
    const float* __restrict__ qbase, const float* __restrict__ kbase,
    const float* __restrict__ vbase, float* __restrict__ outbase,
    _Float16* __restrict__ outh,
    const float* __restrict__ xout_for_loss, float* __restrict__ loss_accum,
    int enc_mode)
{
    const int bh = blockIdx.y;
    const int n0 = blockIdx.x * 64;
    const int t = threadIdx.x;
    const int r = t >> 2;   // row within tile, 0..63
    const int s = t & 3;    // slot 0..3 (owns output dims s*18 .. s*18+17)

    __shared__ float Qs[64 * AT_STRIDE];
    __shared__ float Ks[64 * AT_STRIDE];
    __shared__ float Vs[64 * AT_STRIDE];
    __shared__ float Ps[64 * 65];
    __shared__ float redmax[64 * 4];
    __shared__ float redsum[64 * 4];

    const float* qp = qbase + (size_t)bh * PN * PHD + (size_t)n0 * PHD;
    const float* kp = kbase + (size_t)bh * PN * PHD;
    const float* vp = vbase + (size_t)bh * PN * PHD;

    for (int idx = t; idx < 64 * 18; idx += 256) {
        int row = idx / 18, d4 = idx % 18;
        *(float4*)(&Qs[row * AT_STRIDE + d4 * 4]) =
            *(const float4*)(qp + row * PHD + d4 * 4);
    }

    float O[18];
#pragma unroll
    for (int i = 0; i < 18; ++i) O[i] = 0.f;
    float m_run = -1e30f, l_run = 0.f;

    for (int kt = 0; kt < 16; ++kt) {
        __syncthreads();
        for (int idx = t; idx < 64 * 18; idx += 256) {
            int row = idx / 18, d4 = idx % 18;
            *(float4*)(&Ks[row * AT_STRIDE + d4 * 4]) =
                *(const float4*)(kp + (size_t)kt * 64 * PHD + row * PHD + d4 * 4);
            *(float4*)(&Vs[row * AT_STRIDE + d4 * 4]) =
                *(const float4*)(vp + (size_t)kt * 64 * PHD + row * PHD + d4 * 4);
        }
        __syncthreads();

        float sc[16];
#pragma unroll
        for (int jj = 0; jj < 16; ++jj) sc[jj] = 0.f;
        for (int d4 = 0; d4 < 18; ++d4) {
            float4 q4 = *(const float4*)(&Qs[r * AT_STRIDE + d4 * 4]);
#pragma unroll
            for (int jj = 0; jj < 16; ++jj) {
                int j = jj * 4 + s;
                float4 k4 = *(const float4*)(&Ks[j * AT_STRIDE + d4 * 4]);
                sc[jj] += q4.x * k4.x + q4.y * k4.y + q4.z * k4.z + q4.w * k4.w;
            }
        }

        float lmax = sc[0];
#pragma unroll
        for (int jj = 1; jj < 16; ++jj) lmax = fmaxf(lmax, sc[jj]);
        redmax[r * 4 + s] = lmax;
        __syncthreads();

        float tile_max = fmaxf(fmaxf(redmax[r * 4 + 0], redmax[r * 4 + 1]),
                               fmaxf(redmax[r * 4 + 2], redmax[r * 4 + 3]));
        float m_new = fmaxf(m_run, tile_max);
        float lsum = 0.f;
#pragma unroll
        for (int jj = 0; jj < 16; ++jj) {
            float p = __expf(sc[jj] - m_new);
            Ps[r * 65 + jj * 4 + s] = p;
            lsum += p;
        }
        redsum[r * 4 + s] = lsum;
        float alpha = __expf(m_run - m_new);
        m_run = m_new;
        __syncthreads();

        float tile_sum = redsum[r * 4 + 0] + redsum[r * 4 + 1]
                       + redsum[r * 4 + 2] + redsum[r * 4 + 3];
        l_run = l_run * alpha + tile_sum;
#pragma unroll
        for (int i = 0; i < 18; ++i) O[i] *= alpha;

        const int dbase = s * 18;
        for (int j = 0; j < 64; ++j) {
            float pj = Ps[r * 65 + j];
#pragma unroll
            for (int i2 = 0; i2 < 9; ++i2) {
                float2 v2 = *(const float2*)(&Vs[j * AT_STRIDE + dbase + i2 * 2]);
                O[i2 * 2]     += pj * v2.x;
                O[i2 * 2 + 1] += pj * v2.y;
            }
        }
    }

    float inv_l = 1.0f / l_run;
    int b = bh >> 4, h = bh & 15;
    size_t dst = ((size_t)(b * PN + n0 + r)) * PC + h * PHD + s * 18;

    if (!enc_mode) {
#pragma unroll
        for (int i = 0; i < 18; ++i) {
            float o = O[i] * inv_l;
            outbase[dst + i] = o;
            outh[dst + i]    = (_Float16)o;
        }
    } else {
        float lacc = 0.f;
#pragma unroll
        for (int i = 0; i < 18; ++i) {
            float o = O[i] * inv_l;
            float d = xout_for_loss[dst + i] - o;
            lacc += d * d;
        }
        __syncthreads();
        redsum[t] = lacc;
        __syncthreads();
        for (int off = 128; off > 0; off >>= 1) {
            if (t < off) redsum[t] += redsum[t + off];
            __syncthreads();
        }
        if (t == 0) atomicAdd(loss_accum, redsum[0]);
    }
}

__global__ void finalize_loss(const float* __restrict__ accum, float* __restrict__ dst)
{
    if (threadIdx.x == 0) dst[0] = accum[0] * (1.0f / (float)OUT_ELEMS);
}

// ---------------------------------------------------------------------------
extern "C" void kernel_launch(void* const* d_in, const int* in_sizes, int n_in,
                              void* d_out, int out_size, void* d_ws, size_t ws_size,
                              hipStream_t stream)
{
    const float* x      = (const float*)d_in[0];
    const float* enc_k  = (const float*)d_in[1];
    const float* enc_v  = (const float*)d_in[2];
    const float* qkv_w  = (const float*)d_in[3];
    const float* qkv_b  = (const float*)d_in[4];
    const float* proj_w = (const float*)d_in[5];
    const float* proj_b = (const float*)d_in[6];

    float* out = (float*)d_out;
    float* ws  = (float*)d_ws;

    float* q_ws     = ws;                      // OUT_ELEMS f32
    float* k_ws     = ws + OUT_ELEMS;
    float* v_ws     = ws + 2 * OUT_ELEMS;
    float* xout     = ws + 3 * OUT_ELEMS;
    float* loss_acc = ws + 4 * OUT_ELEMS;      // 1 f32, padded to 8
    float* hbase    = ws + 4 * OUT_ELEMS + 8;

    _Float16* x_h     = (_Float16*)hbase;                  // 4718592
    _Float16* qkvw_h  = x_h + OUT_ELEMS;                   // 3981312
    _Float16* projw_h = qkvw_h + (size_t)QKV_COLS * PC;    // 1327104
    _Float16* xout_h  = projw_h + (size_t)PC * PC;         // 4718592

    const int n8_x  = (int)(OUT_ELEMS / 8);
    const int n8_qw = QKV_COLS * PC / 8;
    const int n8_pw = PC * PC / 8;

    // 0. conversions (independent)
    f32_to_f16<<<(n8_x  + 255) / 256, 256, 0, stream>>>(x,      x_h,     n8_x);
    f32_to_f16<<<(n8_qw + 255) / 256, 256, 0, stream>>>(qkv_w,  qkvw_h,  n8_qw);
    f32_to_f16<<<(n8_pw + 255) / 256, 256, 0, stream>>>(proj_w, projw_h, n8_pw);
    hipMemsetAsync(loss_acc, 0, sizeof(float), stream);

    // 1. QKV projection (MFMA f16), scatter to (BH, N, hd); q pre-scaled
    gemm_mfma<0><<<dim3(QKV_COLS / 128, (PB * PN) / 128), 256, 0, stream>>>(
        x_h, qkvw_h, qkv_b, q_ws, k_ws, v_ws, nullptr);

    // 2. Own-KV attention -> xout (f32, for loss) + xout_h (f16, for proj)
    attn_kernel<<<dim3(PN / 64, BH), 256, 0, stream>>>(
        q_ws, k_ws, v_ws, xout, xout_h, nullptr, nullptr, 0);

    // 3. Output projection (MFMA f16)
    gemm_mfma<1><<<dim3(PC / 128, (PB * PN) / 128), 256, 0, stream>>>(
        xout_h, projw_h, proj_b, nullptr, nullptr, nullptr, out);

    // 4. Encoder-KV attention + fused distill-loss accumulation
    attn_kernel<<<dim3(PN / 64, BH), 256, 0, stream>>>(
        q_ws, enc_k, enc_v, nullptr, nullptr, xout, loss_acc, 1);

    // 5. loss = accum / (B*H*N*hd)
    finalize_loss<<<1, 64, 0, stream>>>(loss_acc, out + OUT_ELEMS);
}

// Round 3
// 480.952 us; speedup vs baseline: 4.2432x; 2.9015x over previous
//
#include <hip/hip_runtime.h>
#include <hip/hip_bf16.h>

// Problem constants: B=4, N=1024, C=1152, H=16, hd=72
#define PB 4
#define PN 1024
#define PC 1152
#define PH 16
#define PHD 72
#define BH 64
#define QKV_COLS 3456
#define OUT_ELEMS ((size_t)PB*PN*PC)   // 4718592
#define K_DIM 1152

// Blocked f16 layouts (per (bh, 64-row chunk), all 6144 halves = 12288 B):
//  q/k:  [dq(12)][row(64)][8]   element (n,d) -> (d>>3)*512 + (n&63)*8 + (d&7)
//  vt :  [kq(8)][hd(96)][8]     element (n,d) -> ((n&63)>>3)*768 + d*8 + (n&7)
#define CHUNK_HALVES 6144
#define HEAD_HALVES (16*CHUNK_HALVES)       // 98304
#define BUF_HALVES ((size_t)BH*HEAD_HALVES) // 6291456 per buffer

typedef _Float16 half8_t __attribute__((ext_vector_type(8)));
typedef float float4v __attribute__((ext_vector_type(4)));

__device__ __forceinline__ void load16_lds(const _Float16* g, _Float16* l) {
    __builtin_amdgcn_global_load_lds(
        (const __attribute__((address_space(1))) void*)g,
        (__attribute__((address_space(3))) void*)l, 16, 0, 0);
}

// ---------------------------------------------------------------------------
// fp32 -> f16 conversion
// ---------------------------------------------------------------------------
__global__ __launch_bounds__(256) void f32_to_f16(
    const float* __restrict__ in, _Float16* __restrict__ out, int n8)
{
    int i = blockIdx.x * 256 + threadIdx.x;
    if (i >= n8) return;
    float4 a = ((const float4*)in)[2 * i];
    float4 b = ((const float4*)in)[2 * i + 1];
    half8_t h;
    h[0] = (_Float16)a.x; h[1] = (_Float16)a.y; h[2] = (_Float16)a.z; h[3] = (_Float16)a.w;
    h[4] = (_Float16)b.x; h[5] = (_Float16)b.y; h[6] = (_Float16)b.z; h[7] = (_Float16)b.w;
    ((half8_t*)out)[i] = h;
}

// ---------------------------------------------------------------------------
// enc_k / enc_v (B,H,N,72 f32) -> blocked f16 (k layout / vt layout)
// ---------------------------------------------------------------------------
__global__ __launch_bounds__(256) void enc_convert(
    const float* __restrict__ ek, const float* __restrict__ ev,
    _Float16* __restrict__ ekh, _Float16* __restrict__ evth)
{
    const int bh = blockIdx.y, nblk = blockIdx.x, t = threadIdx.x;
    const float* ksrc = ek + ((size_t)bh * PN + nblk * 64) * PHD;
    const float* vsrc = ev + ((size_t)bh * PN + nblk * 64) * PHD;
    _Float16* kdst = ekh  + ((size_t)bh * 16 + nblk) * CHUNK_HALVES;
    _Float16* vdst = evth + ((size_t)bh * 16 + nblk) * CHUNK_HALVES;
    for (int i = t; i < 64 * 18; i += 256) {
        int n = i / 18, d4 = (i % 18) * 4;
        float4 kv = *(const float4*)&ksrc[n * PHD + d4];
        float4 vv = *(const float4*)&vsrc[n * PHD + d4];
        float ka[4] = {kv.x, kv.y, kv.z, kv.w};
        float va[4] = {vv.x, vv.y, vv.z, vv.w};
#pragma unroll
        for (int kk = 0; kk < 4; ++kk) {
            int d = d4 + kk;
            kdst[(d >> 3) * 512 + n * 8 + (d & 7)]      = (_Float16)ka[kk];
            vdst[(n >> 3) * 768 + d * 8 + (n & 7)]      = (_Float16)va[kk];
        }
    }
}

// ---------------------------------------------------------------------------
// MFMA f16 GEMM, 128x128 tile, BK=64 (m97 recipe).
// MODE 0: QKV epilogue -> blocked f16 q/k/vt (q pre-scaled)
// MODE 1: proj epilogue -> f32 (M,C) + bias
// ---------------------------------------------------------------------------
template<int MODE>
__global__ __launch_bounds__(256) void gemm_mfma(
    const _Float16* __restrict__ A, const _Float16* __restrict__ Bm,
    const float* __restrict__ bias,
    _Float16* __restrict__ qh, _Float16* __restrict__ kh,
    _Float16* __restrict__ vth, float* __restrict__ out)
{
    const int t    = threadIdx.x;
    const int lane = t & 63;
    const int w    = t >> 6;
    const int wm   = w >> 1, wn = w & 1;
    const int lrow = lane & 15, quad = lane >> 4;
    const int m0   = blockIdx.y * 128;
    const int c0   = blockIdx.x * 128;

    __shared__ _Float16 As[8192];
    __shared__ _Float16 Bs[8192];

    int rowS[4], koff[4], ldsOff[4];
#pragma unroll
    for (int i = 0; i < 4; ++i) {
        int idx = w * 256 + i * 64 + lane;
        int kt2 = idx >> 9, qq = (idx >> 7) & 3;
        rowS[i]   = idx & 127;
        koff[i]   = kt2 * 32 + qq * 8;
        ldsOff[i] = idx * 8;
    }

    const _Float16* aBase = A  + (size_t)m0 * K_DIM;
    const _Float16* bBase = Bm + (size_t)c0 * K_DIM;

    float4v acc[4][4];
#pragma unroll
    for (int ti = 0; ti < 4; ++ti)
#pragma unroll
        for (int tj = 0; tj < 4; ++tj)
            acc[ti][tj] = (float4v){0.f, 0.f, 0.f, 0.f};

    for (int kb = 0; kb < K_DIM; kb += 64) {
        __syncthreads();
#pragma unroll
        for (int i = 0; i < 4; ++i) {
            load16_lds(aBase + (size_t)rowS[i] * K_DIM + kb + koff[i], &As[ldsOff[i]]);
            load16_lds(bBase + (size_t)rowS[i] * K_DIM + kb + koff[i], &Bs[ldsOff[i]]);
        }
        __syncthreads();
#pragma unroll
        for (int s = 0; s < 2; ++s) {
            half8_t af[4], bf[4];
#pragma unroll
            for (int ti = 0; ti < 4; ++ti)
                af[ti] = *(const half8_t*)&As[(((s * 4 + quad) * 128) + wm * 64 + ti * 16 + lrow) * 8];
#pragma unroll
            for (int tj = 0; tj < 4; ++tj)
                bf[tj] = *(const half8_t*)&Bs[(((s * 4 + quad) * 128) + wn * 64 + tj * 16 + lrow) * 8];
#pragma unroll
            for (int ti = 0; ti < 4; ++ti)
#pragma unroll
                for (int tj = 0; tj < 4; ++tj)
                    acc[ti][tj] = __builtin_amdgcn_mfma_f32_16x16x32_f16(
                        af[ti], bf[tj], acc[ti][tj], 0, 0, 0);
        }
    }

    // C/D layout: col = lane&15, row = quad*4 + reg (m91-verified).
    if (MODE == 0) {
        const float scale = 0.11785113019775792f; // 72^-0.5
#pragma unroll
        for (int tj = 0; tj < 4; ++tj) {
            int c = c0 + wn * 64 + tj * 16 + lrow;
            float bv = bias[c];
            int jq  = c / PC;
            int rem = c - jq * PC;
            int h   = rem / PHD;
            int d   = rem - h * PHD;
#pragma unroll
            for (int ti = 0; ti < 4; ++ti)
#pragma unroll
                for (int r = 0; r < 4; ++r) {
                    int m = m0 + wm * 64 + ti * 16 + quad * 4 + r;
                    int b = m >> 10, n = m & 1023;
                    int bh = b * PH + h;
                    size_t chunk = ((size_t)bh * 16 + (n >> 6)) * CHUNK_HALVES;
                    float val = acc[ti][tj][r] + bv;
                    if (jq == 0)
                        qh[chunk + (d >> 3) * 512 + (n & 63) * 8 + (d & 7)] = (_Float16)(val * scale);
                    else if (jq == 1)
                        kh[chunk + (d >> 3) * 512 + (n & 63) * 8 + (d & 7)] = (_Float16)val;
                    else
                        vth[chunk + ((n & 63) >> 3) * 768 + d * 8 + (n & 7)] = (_Float16)val;
                }
        }
    } else {
#pragma unroll
        for (int tj = 0; tj < 4; ++tj) {
            int c = c0 + wn * 64 + tj * 16 + lrow;
            float bv = bias[c];
#pragma unroll
            for (int ti = 0; ti < 4; ++ti)
#pragma unroll
                for (int r = 0; r < 4; ++r) {
                    int m = m0 + wm * 64 + ti * 16 + quad * 4 + r;
                    out[(size_t)m * PC + c] = acc[ti][tj][r] + bv;
                }
        }
    }
}

// ---------------------------------------------------------------------------
// MFMA flash attention. Block = (nblk, bh): 64 Q-rows, 4 waves x 16 rows.
// Q/K padded hd->96 (3 K-steps of 32); V transposed (96 x N chunk), PV gets
// contiguous B-fragments. P round-trips LDS per-wave (no barrier).
// ---------------------------------------------------------------------------
__global__ __launch_bounds__(256) void attn_mfma(
    const _Float16* __restrict__ qh, const _Float16* __restrict__ kh,
    const _Float16* __restrict__ vth,
    float* __restrict__ xout, _Float16* __restrict__ xouth,
    const float* __restrict__ xref, float* __restrict__ loss_accum,
    int enc_mode)
{
    const int t = threadIdx.x;
    const int lane = t & 63;
    const int w = t >> 6;
    const int ln = lane & 15;
    const int quad = lane >> 4;
    const int bh = blockIdx.y;
    const int nblk = blockIdx.x;

    __shared__ _Float16 Qs[CHUNK_HALVES];
    __shared__ _Float16 Ks[CHUNK_HALVES];
    __shared__ _Float16 Vts[CHUNK_HALVES];
    __shared__ _Float16 Ps[4096];   // per-wave [8 kq][16 rows][8]
    __shared__ float red[256];

    const _Float16* qc = qh  + ((size_t)bh * 16 + nblk) * CHUNK_HALVES;
    const _Float16* kb = kh  + (size_t)bh * HEAD_HALVES;
    const _Float16* vb = vth + (size_t)bh * HEAD_HALVES;

    // stage Q once (768 x 16B, contiguous)
#pragma unroll
    for (int i = 0; i < 3; ++i) {
        int u = i * 256 + t;
        load16_lds(qc + u * 8, &Qs[u * 8]);
    }

    float4v O[5];
#pragma unroll
    for (int ct = 0; ct < 5; ++ct) O[ct] = (float4v){0.f, 0.f, 0.f, 0.f};
    float m_run[4] = {-1e30f, -1e30f, -1e30f, -1e30f};
    float l_run[4] = {0.f, 0.f, 0.f, 0.f};

    for (int kt = 0; kt < 16; ++kt) {
        __syncthreads();  // prev chunk's PV done with Vts/Ks
        const _Float16* kc = kb + (size_t)kt * CHUNK_HALVES;
        const _Float16* vc = vb + (size_t)kt * CHUNK_HALVES;
#pragma unroll
        for (int i = 0; i < 3; ++i) {
            int u = i * 256 + t;
            load16_lds(kc + u * 8, &Ks[u * 8]);
            load16_lds(vc + u * 8, &Vts[u * 8]);
        }
        __syncthreads();  // DMA drained (covers Qs on first iter)

        // S = Q K^T  (16 rows x 64 cols per wave)
        float4v accS[4];
#pragma unroll
        for (int ct = 0; ct < 4; ++ct) accS[ct] = (float4v){0.f, 0.f, 0.f, 0.f};
#pragma unroll
        for (int ks = 0; ks < 3; ++ks) {
            half8_t af = *(const half8_t*)&Qs[(((ks * 4 + quad) * 64) + w * 16 + ln) * 8];
#pragma unroll
            for (int ct = 0; ct < 4; ++ct) {
                half8_t bf = *(const half8_t*)&Ks[(((ks * 4 + quad) * 64) + ct * 16 + ln) * 8];
                accS[ct] = __builtin_amdgcn_mfma_f32_16x16x32_f16(af, bf, accS[ct], 0, 0, 0);
            }
        }

        // online softmax. C row = quad*4+r (lane-replicated over ln group)
        float rowmax[4], alpha[4], lsum[4];
#pragma unroll
        for (int r = 0; r < 4; ++r) {
            float mx = fmaxf(fmaxf(accS[0][r], accS[1][r]), fmaxf(accS[2][r], accS[3][r]));
#pragma unroll
            for (int mask = 1; mask < 16; mask <<= 1)
                mx = fmaxf(mx, __shfl_xor(mx, mask));
            float m_new = fmaxf(m_run[r], mx);
            alpha[r] = __expf(m_run[r] - m_new);
            m_run[r] = m_new;
            lsum[r] = 0.f;
        }
#pragma unroll
        for (int ct = 0; ct < 4; ++ct) {
            int kcol = ct * 16 + ln;
            int pbase = (w * 8 + (kcol >> 3)) * 128 + (kcol & 7);
#pragma unroll
            for (int r = 0; r < 4; ++r) {
                float p = __expf(accS[ct][r] - m_run[r]);
                lsum[r] += p;
                Ps[pbase + (quad * 4 + r) * 8] = (_Float16)p;
            }
        }
#pragma unroll
        for (int r = 0; r < 4; ++r) {
#pragma unroll
            for (int mask = 1; mask < 16; mask <<= 1)
                lsum[r] += __shfl_xor(lsum[r], mask);
            l_run[r] = l_run[r] * alpha[r] + lsum[r];
        }
#pragma unroll
        for (int ct = 0; ct < 5; ++ct)
#pragma unroll
            for (int r = 0; r < 4; ++r) O[ct][r] *= alpha[r];

        // PV: A = P (wave-local LDS), B = Vt
#pragma unroll
        for (int ks = 0; ks < 2; ++ks) {
            half8_t pa = *(const half8_t*)&Ps[((w * 8 + ks * 4 + quad) * 16 + ln) * 8];
#pragma unroll
            for (int ct = 0; ct < 5; ++ct) {
                half8_t vf = *(const half8_t*)&Vts[(((ks * 4 + quad) * 96) + ct * 16 + ln) * 8];
                O[ct] = __builtin_amdgcn_mfma_f32_16x16x32_f16(pa, vf, O[ct], 0, 0, 0);
            }
        }
    }

    float inv_l[4];
#pragma unroll
    for (int r = 0; r < 4; ++r) inv_l[r] = 1.0f / l_run[r];

    const int b = bh >> 4, h = bh & 15;
    const int nrow = nblk * 64 + w * 16 + quad * 4;

    if (!enc_mode) {
#pragma unroll
        for (int ct = 0; ct < 5; ++ct) {
            int d = ct * 16 + ln;
            if (d < PHD) {
#pragma unroll
                for (int r = 0; r < 4; ++r) {
                    size_t idx = ((size_t)(b * PN + nrow + r)) * PC + h * PHD + d;
                    float o = O[ct][r] * inv_l[r];
                    xout[idx]  = o;
                    xouth[idx] = (_Float16)o;
                }
            }
        }
    } else {
        float lacc = 0.f;
#pragma unroll
        for (int ct = 0; ct < 5; ++ct) {
            int d = ct * 16 + ln;
            if (d < PHD) {
#pragma unroll
                for (int r = 0; r < 4; ++r) {
                    size_t idx = ((size_t)(b * PN + nrow + r)) * PC + h * PHD + d;
                    float o = O[ct][r] * inv_l[r];
                    float df = xref[idx] - o;
                    lacc += df * df;
                }
            }
        }
        red[t] = lacc;
        __syncthreads();
        for (int off = 128; off > 0; off >>= 1) {
            if (t < off) red[t] += red[t + off];
            __syncthreads();
        }
        if (t == 0) atomicAdd(loss_accum, red[0]);
    }
}

__global__ void finalize_loss(const float* __restrict__ accum, float* __restrict__ dst)
{
    if (threadIdx.x == 0) dst[0] = accum[0] * (1.0f / (float)OUT_ELEMS);
}

// ---------------------------------------------------------------------------
extern "C" void kernel_launch(void* const* d_in, const int* in_sizes, int n_in,
                              void* d_out, int out_size, void* d_ws, size_t ws_size,
                              hipStream_t stream)
{
    const float* x      = (const float*)d_in[0];
    const float* enc_k  = (const float*)d_in[1];
    const float* enc_v  = (const float*)d_in[2];
    const float* qkv_w  = (const float*)d_in[3];
    const float* qkv_b  = (const float*)d_in[4];
    const float* proj_w = (const float*)d_in[5];
    const float* proj_b = (const float*)d_in[6];

    float* out = (float*)d_out;
    float* ws  = (float*)d_ws;

    float* xout     = ws;                       // OUT_ELEMS f32
    float* loss_acc = ws + OUT_ELEMS;           // 1 f32 (pad 8)

    _Float16* x_h     = (_Float16*)(ws + OUT_ELEMS + 8);
    _Float16* qkvw_h  = x_h + OUT_ELEMS;
    _Float16* projw_h = qkvw_h + (size_t)QKV_COLS * PC;
    _Float16* xout_h  = projw_h + (size_t)PC * PC;
    _Float16* q_h     = xout_h + OUT_ELEMS;     // 5 blocked buffers, contiguous
    _Float16* k_h     = q_h  + BUF_HALVES;
    _Float16* vt_h    = k_h  + BUF_HALVES;
    _Float16* ek_h    = vt_h + BUF_HALVES;
    _Float16* evt_h   = ek_h + BUF_HALVES;

    const int n8_x  = (int)(OUT_ELEMS / 8);
    const int n8_qw = QKV_COLS * PC / 8;
    const int n8_pw = PC * PC / 8;

    // 0. zero pads (one contiguous memset over the 5 blocked buffers) + loss
    hipMemsetAsync(q_h, 0, 5 * BUF_HALVES * sizeof(_Float16), stream);
    hipMemsetAsync(loss_acc, 0, sizeof(float), stream);

    // conversions
    f32_to_f16<<<(n8_x  + 255) / 256, 256, 0, stream>>>(x,      x_h,     n8_x);
    f32_to_f16<<<(n8_qw + 255) / 256, 256, 0, stream>>>(qkv_w,  qkvw_h,  n8_qw);
    f32_to_f16<<<(n8_pw + 255) / 256, 256, 0, stream>>>(proj_w, projw_h, n8_pw);
    enc_convert<<<dim3(16, BH), 256, 0, stream>>>(enc_k, enc_v, ek_h, evt_h);

    // 1. QKV projection -> blocked f16 q/k/vt (q pre-scaled)
    gemm_mfma<0><<<dim3(QKV_COLS / 128, (PB * PN) / 128), 256, 0, stream>>>(
        x_h, qkvw_h, qkv_b, q_h, k_h, vt_h, nullptr);

    // 2. Own-KV attention -> xout (f32) + xout_h (f16)
    attn_mfma<<<dim3(16, BH), 256, 0, stream>>>(
        q_h, k_h, vt_h, xout, xout_h, nullptr, nullptr, 0);

    // 3. Output projection
    gemm_mfma<1><<<dim3(PC / 128, (PB * PN) / 128), 256, 0, stream>>>(
        xout_h, projw_h, proj_b, nullptr, nullptr, nullptr, out);

    // 4. Encoder-KV attention + fused distill loss
    attn_mfma<<<dim3(16, BH), 256, 0, stream>>>(
        q_h, ek_h, evt_h, nullptr, nullptr, xout, loss_acc, 1);

    // 5. loss = accum / (B*H*N*hd)
    finalize_loss<<<1, 64, 0, stream>>>(loss_acc, out + OUT_ELEMS);
}

// Round 4
// 424.177 us; speedup vs baseline: 4.8112x; 1.1338x over previous
//
#include <hip/hip_runtime.h>
#include <hip/hip_bf16.h>

// Problem constants: B=4, N=1024, C=1152, H=16, hd=72
#define PB 4
#define PN 1024
#define PC 1152
#define PH 16
#define PHD 72
#define BH 64
#define QKV_COLS 3456
#define OUT_ELEMS ((size_t)PB*PN*PC)   // 4718592
#define K_DIM 1152

// Blocked f16 layouts (per (bh, 64-row chunk), 6144 halves = 12288 B):
//  q/k:  [dq(12)][row(64)][8]   element (n,d) -> (d>>3)*512 + (n&63)*8 + (d&7)
//  vt :  [kq(8)][hd(96)][8]     element (n,d) -> ((n&63)>>3)*768 + d*8 + (n&7)
#define CHUNK_HALVES 6144
#define HEAD_HALVES (16*CHUNK_HALVES)       // 98304
#define BUF_HALVES ((size_t)BH*HEAD_HALVES) // 6291456 per buffer

typedef _Float16 half8_t __attribute__((ext_vector_type(8)));
typedef float float4v __attribute__((ext_vector_type(4)));

__device__ __forceinline__ void load16_lds(const _Float16* g, _Float16* l) {
    __builtin_amdgcn_global_load_lds(
        (const __attribute__((address_space(1))) void*)g,
        (__attribute__((address_space(3))) void*)l, 16, 0, 0);
}

// ---------------------------------------------------------------------------
// fp32 -> f16 conversion
// ---------------------------------------------------------------------------
__global__ __launch_bounds__(256) void f32_to_f16(
    const float* __restrict__ in, _Float16* __restrict__ out, int n8)
{
    int i = blockIdx.x * 256 + threadIdx.x;
    if (i >= n8) return;
    float4 a = ((const float4*)in)[2 * i];
    float4 b = ((const float4*)in)[2 * i + 1];
    half8_t h;
    h[0] = (_Float16)a.x; h[1] = (_Float16)a.y; h[2] = (_Float16)a.z; h[3] = (_Float16)a.w;
    h[4] = (_Float16)b.x; h[5] = (_Float16)b.y; h[6] = (_Float16)b.z; h[7] = (_Float16)b.w;
    ((half8_t*)out)[i] = h;
}

// ---------------------------------------------------------------------------
// Zero q_h pad lanes (d=72..95): per chunk halves [4608, 6144)
// ---------------------------------------------------------------------------
__global__ __launch_bounds__(256) void zero_qpad(_Float16* __restrict__ qh)
{
    int i = blockIdx.x * 256 + threadIdx.x;   // 196608 total half8s
    int chunk = i / 192, within = i - chunk * 192;
    half8_t z = {};
    *(half8_t*)(qh + (size_t)chunk * CHUNK_HALVES + 4608 + within * 8) = z;
}

// ---------------------------------------------------------------------------
// enc_k / enc_v (B,H,N,72 f32) -> blocked f16 (k layout / vt layout)
// ---------------------------------------------------------------------------
__global__ __launch_bounds__(256) void enc_convert(
    const float* __restrict__ ek, const float* __restrict__ ev,
    _Float16* __restrict__ ekh, _Float16* __restrict__ evth)
{
    const int bh = blockIdx.y, nblk = blockIdx.x, t = threadIdx.x;
    const float* ksrc = ek + ((size_t)bh * PN + nblk * 64) * PHD;
    const float* vsrc = ev + ((size_t)bh * PN + nblk * 64) * PHD;
    _Float16* kdst = ekh  + ((size_t)bh * 16 + nblk) * CHUNK_HALVES;
    _Float16* vdst = evth + ((size_t)bh * 16 + nblk) * CHUNK_HALVES;
    for (int i = t; i < 64 * 18; i += 256) {
        int n = i / 18, d4 = (i % 18) * 4;
        float4 kv = *(const float4*)&ksrc[n * PHD + d4];
        float4 vv = *(const float4*)&vsrc[n * PHD + d4];
        float ka[4] = {kv.x, kv.y, kv.z, kv.w};
        float va[4] = {vv.x, vv.y, vv.z, vv.w};
#pragma unroll
        for (int kk = 0; kk < 4; ++kk) {
            int d = d4 + kk;
            kdst[(d >> 3) * 512 + n * 8 + (d & 7)] = (_Float16)ka[kk];
            vdst[(n >> 3) * 768 + d * 8 + (n & 7)] = (_Float16)va[kk];
        }
    }
}

// ---------------------------------------------------------------------------
// MFMA f16 GEMM, 128x128 tile, BK=64, grouped-swizzle 1D grid.
// MODE 0: QKV epilogue -> blocked f16 q/k/vt (q pre-scaled)
// MODE 1: proj epilogue -> f32 (M,C) + bias
// ---------------------------------------------------------------------------
template<int MODE>
__global__ __launch_bounds__(256) void gemm_mfma(
    const _Float16* __restrict__ A, const _Float16* __restrict__ Bm,
    const float* __restrict__ bias,
    _Float16* __restrict__ qh, _Float16* __restrict__ kh,
    _Float16* __restrict__ vth, float* __restrict__ out, int c_tiles)
{
    const int t    = threadIdx.x;
    const int lane = t & 63;
    const int w    = t >> 6;
    const int wm   = w >> 1, wn = w & 1;
    const int lrow = lane & 15, quad = lane >> 4;

    // grouped swizzle: 8 m-tiles x all c-tiles per group (A panel L2-resident)
    const int per_group = c_tiles * 8;
    const int g  = blockIdx.x / per_group;
    const int r_ = blockIdx.x - g * per_group;
    const int m0 = (g * 8 + (r_ & 7)) * 128;
    const int c0 = (r_ >> 3) * 128;

    __shared__ _Float16 As[8192];
    __shared__ _Float16 Bs[8192];

    int rowS[4], koff[4], ldsOff[4];
#pragma unroll
    for (int i = 0; i < 4; ++i) {
        int idx = w * 256 + i * 64 + lane;
        int kt2 = idx >> 9, qq = (idx >> 7) & 3;
        rowS[i]   = idx & 127;
        koff[i]   = kt2 * 32 + qq * 8;
        ldsOff[i] = idx * 8;
    }

    const _Float16* aBase = A  + (size_t)m0 * K_DIM;
    const _Float16* bBase = Bm + (size_t)c0 * K_DIM;

    float4v acc[4][4];
#pragma unroll
    for (int ti = 0; ti < 4; ++ti)
#pragma unroll
        for (int tj = 0; tj < 4; ++tj)
            acc[ti][tj] = (float4v){0.f, 0.f, 0.f, 0.f};

    for (int kb = 0; kb < K_DIM; kb += 64) {
        __syncthreads();
#pragma unroll
        for (int i = 0; i < 4; ++i) {
            load16_lds(aBase + (size_t)rowS[i] * K_DIM + kb + koff[i], &As[ldsOff[i]]);
            load16_lds(bBase + (size_t)rowS[i] * K_DIM + kb + koff[i], &Bs[ldsOff[i]]);
        }
        __syncthreads();
#pragma unroll
        for (int s = 0; s < 2; ++s) {
            half8_t af[4], bf[4];
#pragma unroll
            for (int ti = 0; ti < 4; ++ti)
                af[ti] = *(const half8_t*)&As[(((s * 4 + quad) * 128) + wm * 64 + ti * 16 + lrow) * 8];
#pragma unroll
            for (int tj = 0; tj < 4; ++tj)
                bf[tj] = *(const half8_t*)&Bs[(((s * 4 + quad) * 128) + wn * 64 + tj * 16 + lrow) * 8];
#pragma unroll
            for (int ti = 0; ti < 4; ++ti)
#pragma unroll
                for (int tj = 0; tj < 4; ++tj)
                    acc[ti][tj] = __builtin_amdgcn_mfma_f32_16x16x32_f16(
                        af[ti], bf[tj], acc[ti][tj], 0, 0, 0);
        }
    }

    // C/D layout: col = lane&15, row = quad*4 + reg (m91-verified).
    if (MODE == 0) {
        const float scale = 0.11785113019775792f; // 72^-0.5
#pragma unroll
        for (int tj = 0; tj < 4; ++tj) {
            int c = c0 + wn * 64 + tj * 16 + lrow;
            float bv = bias[c];
            int jq  = c / PC;
            int rem = c - jq * PC;
            int h   = rem / PHD;
            int d   = rem - h * PHD;
#pragma unroll
            for (int ti = 0; ti < 4; ++ti)
#pragma unroll
                for (int r = 0; r < 4; ++r) {
                    int m = m0 + wm * 64 + ti * 16 + quad * 4 + r;
                    int b = m >> 10, n = m & 1023;
                    int bh = b * PH + h;
                    size_t chunk = ((size_t)bh * 16 + (n >> 6)) * CHUNK_HALVES;
                    float val = acc[ti][tj][r] + bv;
                    if (jq == 0)
                        qh[chunk + (d >> 3) * 512 + (n & 63) * 8 + (d & 7)] = (_Float16)(val * scale);
                    else if (jq == 1)
                        kh[chunk + (d >> 3) * 512 + (n & 63) * 8 + (d & 7)] = (_Float16)val;
                    else
                        vth[chunk + ((n & 63) >> 3) * 768 + d * 8 + (n & 7)] = (_Float16)val;
                }
        }
    } else {
#pragma unroll
        for (int tj = 0; tj < 4; ++tj) {
            int c = c0 + wn * 64 + tj * 16 + lrow;
            float bv = bias[c];
#pragma unroll
            for (int ti = 0; ti < 4; ++ti)
#pragma unroll
                for (int r = 0; r < 4; ++r) {
                    int m = m0 + wm * 64 + ti * 16 + quad * 4 + r;
                    out[(size_t)m * PC + c] = acc[ti][tj][r] + bv;
                }
        }
    }
}

// ---------------------------------------------------------------------------
// Fused MFMA flash attention: own-KV pass (-> xout_h) then enc-KV pass
// (-> in-register o_star), loss computed in fp32 registers, atomicAdd'ed
// pre-scaled into loss_out. XCD-affinity swizzle: all 16 blocks of a head
// share an XCD for K/V L2 reuse.
// ---------------------------------------------------------------------------
__global__ __launch_bounds__(256) void attn_fused(
    const _Float16* __restrict__ qh, const _Float16* __restrict__ kh,
    const _Float16* __restrict__ vth,
    const _Float16* __restrict__ ekh, const _Float16* __restrict__ evth,
    _Float16* __restrict__ xouth, float* __restrict__ loss_out)
{
    const int t = threadIdx.x;
    const int lane = t & 63;
    const int w = t >> 6;
    const int ln = lane & 15;
    const int quad = lane >> 4;

    const int lid  = blockIdx.x;             // 1024 blocks
    const int bh   = (lid & 7) * 8 + ((lid >> 3) >> 4);
    const int nblk = (lid >> 3) & 15;

    __shared__ _Float16 Qs[CHUNK_HALVES];
    __shared__ _Float16 Ks[CHUNK_HALVES];
    __shared__ _Float16 Vts[CHUNK_HALVES];
    __shared__ _Float16 Ps[4096];   // per-wave [8 kq][16 rows][8]
    __shared__ float red[256];

    const _Float16* qc = qh + ((size_t)bh * 16 + nblk) * CHUNK_HALVES;

    // stage Q once (768 x 16B, contiguous)
#pragma unroll
    for (int i = 0; i < 3; ++i) {
        int u = i * 256 + t;
        load16_lds(qc + u * 8, &Qs[u * 8]);
    }

    float4v own[5];
    float inv_own[4];
    float lacc = 0.f;

    for (int pass = 0; pass < 2; ++pass) {
        const _Float16* kb = (pass ? ekh : kh)  + (size_t)bh * HEAD_HALVES;
        const _Float16* vb = (pass ? evth : vth) + (size_t)bh * HEAD_HALVES;

        float4v O[5];
#pragma unroll
        for (int ct = 0; ct < 5; ++ct) O[ct] = (float4v){0.f, 0.f, 0.f, 0.f};
        float m_run[4] = {-1e30f, -1e30f, -1e30f, -1e30f};
        float l_run[4] = {0.f, 0.f, 0.f, 0.f};

        for (int kt = 0; kt < 16; ++kt) {
            __syncthreads();  // prev chunk's PV done with Ks/Vts
            const _Float16* kc = kb + (size_t)kt * CHUNK_HALVES;
            const _Float16* vc = vb + (size_t)kt * CHUNK_HALVES;
#pragma unroll
            for (int i = 0; i < 3; ++i) {
                int u = i * 256 + t;
                load16_lds(kc + u * 8, &Ks[u * 8]);
                load16_lds(vc + u * 8, &Vts[u * 8]);
            }
            __syncthreads();  // DMA drained (covers Qs on first iter)

            // S = Q K^T  (16 rows x 64 cols per wave)
            float4v accS[4];
#pragma unroll
            for (int ct = 0; ct < 4; ++ct) accS[ct] = (float4v){0.f, 0.f, 0.f, 0.f};
#pragma unroll
            for (int ks = 0; ks < 3; ++ks) {
                half8_t af = *(const half8_t*)&Qs[(((ks * 4 + quad) * 64) + w * 16 + ln) * 8];
#pragma unroll
                for (int ct = 0; ct < 4; ++ct) {
                    half8_t bf = *(const half8_t*)&Ks[(((ks * 4 + quad) * 64) + ct * 16 + ln) * 8];
                    accS[ct] = __builtin_amdgcn_mfma_f32_16x16x32_f16(af, bf, accS[ct], 0, 0, 0);
                }
            }

            // online softmax; C row = quad*4+r
            float alpha[4], lsum[4];
#pragma unroll
            for (int r = 0; r < 4; ++r) {
                float mx = fmaxf(fmaxf(accS[0][r], accS[1][r]), fmaxf(accS[2][r], accS[3][r]));
#pragma unroll
                for (int mask = 1; mask < 16; mask <<= 1)
                    mx = fmaxf(mx, __shfl_xor(mx, mask));
                float m_new = fmaxf(m_run[r], mx);
                alpha[r] = __expf(m_run[r] - m_new);
                m_run[r] = m_new;
                lsum[r] = 0.f;
            }
#pragma unroll
            for (int ct = 0; ct < 4; ++ct) {
                int kcol = ct * 16 + ln;
                int pbase = (w * 8 + (kcol >> 3)) * 128 + (kcol & 7);
#pragma unroll
                for (int r = 0; r < 4; ++r) {
                    float p = __expf(accS[ct][r] - m_run[r]);
                    lsum[r] += p;
                    Ps[pbase + (quad * 4 + r) * 8] = (_Float16)p;
                }
            }
#pragma unroll
            for (int r = 0; r < 4; ++r) {
#pragma unroll
                for (int mask = 1; mask < 16; mask <<= 1)
                    lsum[r] += __shfl_xor(lsum[r], mask);
                l_run[r] = l_run[r] * alpha[r] + lsum[r];
            }
#pragma unroll
            for (int ct = 0; ct < 5; ++ct)
#pragma unroll
                for (int r = 0; r < 4; ++r) O[ct][r] *= alpha[r];

            // PV: A = P (wave-local LDS), B = Vt
#pragma unroll
            for (int ks = 0; ks < 2; ++ks) {
                half8_t pa = *(const half8_t*)&Ps[((w * 8 + ks * 4 + quad) * 16 + ln) * 8];
#pragma unroll
                for (int ct = 0; ct < 5; ++ct) {
                    half8_t vf = *(const half8_t*)&Vts[(((ks * 4 + quad) * 96) + ct * 16 + ln) * 8];
                    O[ct] = __builtin_amdgcn_mfma_f32_16x16x32_f16(pa, vf, O[ct], 0, 0, 0);
                }
            }
        }

        float inv_l[4];
#pragma unroll
        for (int r = 0; r < 4; ++r) inv_l[r] = 1.0f / l_run[r];

        if (pass == 0) {
#pragma unroll
            for (int ct = 0; ct < 5; ++ct)
#pragma unroll
                for (int r = 0; r < 4; ++r) own[ct][r] = O[ct][r] * inv_l[r];
#pragma unroll
            for (int r = 0; r < 4; ++r) inv_own[r] = inv_l[r];  // keep regs alive
            // write xout_h (f16) for proj GEMM
            const int b = bh >> 4, h = bh & 15;
            const int nrow = nblk * 64 + w * 16 + quad * 4;
#pragma unroll
            for (int ct = 0; ct < 5; ++ct) {
                int d = ct * 16 + ln;
                if (d < PHD) {
#pragma unroll
                    for (int r = 0; r < 4; ++r) {
                        size_t idx = ((size_t)(b * PN + nrow + r)) * PC + h * PHD + d;
                        xouth[idx] = (_Float16)own[ct][r];
                    }
                }
            }
        } else {
#pragma unroll
            for (int ct = 0; ct < 5; ++ct) {
                int d = ct * 16 + ln;
                if (d < PHD) {
#pragma unroll
                    for (int r = 0; r < 4; ++r) {
                        float df = own[ct][r] - O[ct][r] * inv_l[r];
                        lacc += df * df;
                    }
                }
            }
        }
    }

    red[t] = lacc;
    __syncthreads();
    for (int off = 128; off > 0; off >>= 1) {
        if (t < off) red[t] += red[t + off];
        __syncthreads();
    }
    if (t == 0) atomicAdd(loss_out, red[0] * (1.0f / (float)OUT_ELEMS));
}

// ---------------------------------------------------------------------------
extern "C" void kernel_launch(void* const* d_in, const int* in_sizes, int n_in,
                              void* d_out, int out_size, void* d_ws, size_t ws_size,
                              hipStream_t stream)
{
    const float* x      = (const float*)d_in[0];
    const float* enc_k  = (const float*)d_in[1];
    const float* enc_v  = (const float*)d_in[2];
    const float* qkv_w  = (const float*)d_in[3];
    const float* qkv_b  = (const float*)d_in[4];
    const float* proj_w = (const float*)d_in[5];
    const float* proj_b = (const float*)d_in[6];

    float* out = (float*)d_out;

    _Float16* x_h     = (_Float16*)d_ws;
    _Float16* qkvw_h  = x_h + OUT_ELEMS;
    _Float16* projw_h = qkvw_h + (size_t)QKV_COLS * PC;
    _Float16* xout_h  = projw_h + (size_t)PC * PC;
    _Float16* q_h     = xout_h + OUT_ELEMS;
    _Float16* k_h     = q_h  + BUF_HALVES;
    _Float16* vt_h    = k_h  + BUF_HALVES;
    _Float16* ek_h    = vt_h + BUF_HALVES;
    _Float16* evt_h   = ek_h + BUF_HALVES;

    const int n8_x  = (int)(OUT_ELEMS / 8);
    const int n8_qw = QKV_COLS * PC / 8;
    const int n8_pw = PC * PC / 8;

    // 0. zero loss slot + q pads
    hipMemsetAsync(out + OUT_ELEMS, 0, sizeof(float), stream);
    zero_qpad<<<768, 256, 0, stream>>>(q_h);

    // conversions
    f32_to_f16<<<(n8_x  + 255) / 256, 256, 0, stream>>>(x,      x_h,     n8_x);
    f32_to_f16<<<(n8_qw + 255) / 256, 256, 0, stream>>>(qkv_w,  qkvw_h,  n8_qw);
    f32_to_f16<<<(n8_pw + 255) / 256, 256, 0, stream>>>(proj_w, projw_h, n8_pw);
    enc_convert<<<dim3(16, BH), 256, 0, stream>>>(enc_k, enc_v, ek_h, evt_h);

    // 1. QKV projection -> blocked f16 q/k/vt (q pre-scaled); 27 c-tiles
    gemm_mfma<0><<<(QKV_COLS / 128) * ((PB * PN) / 128), 256, 0, stream>>>(
        x_h, qkvw_h, qkv_b, q_h, k_h, vt_h, nullptr, QKV_COLS / 128);

    // 2. Fused own+enc attention -> xout_h + loss into out[OUT_ELEMS]
    attn_fused<<<16 * BH, 256, 0, stream>>>(
        q_h, k_h, vt_h, ek_h, evt_h, xout_h, out + OUT_ELEMS);

    // 3. Output projection; 9 c-tiles
    gemm_mfma<1><<<(PC / 128) * ((PB * PN) / 128), 256, 0, stream>>>(
        xout_h, projw_h, proj_b, nullptr, nullptr, nullptr, out, PC / 128);
}

// Round 5
// 397.737 us; speedup vs baseline: 5.1310x; 1.0665x over previous
//
#include <hip/hip_runtime.h>
#include <hip/hip_bf16.h>

// Problem constants: B=4, N=1024, C=1152, H=16, hd=72
#define PB 4
#define PN 1024
#define PC 1152
#define PH 16
#define PHD 72
#define BH 64
#define QKV_COLS 3456
#define OUT_ELEMS ((size_t)PB*PN*PC)   // 4718592
#define K_DIM 1152

// Blocked f16 layouts (per (bh, 64-row chunk), 6144 halves = 12288 B):
//  q/k:  [dq(12)][row(64)][8]   element (n,d) -> (d>>3)*512 + (n&63)*8 + (d&7)
//  vt :  [kq(8)][hd(96)][8]     element (n,d) -> ((n&63)>>3)*768 + d*8 + (n&7)
#define CHUNK_HALVES 6144
#define HEAD_HALVES (16*CHUNK_HALVES)       // 98304
#define BUF_HALVES ((size_t)BH*HEAD_HALVES) // 6291456 per buffer

typedef _Float16 half8_t __attribute__((ext_vector_type(8)));
typedef float float4v __attribute__((ext_vector_type(4)));

__device__ __forceinline__ void load16_lds(const _Float16* g, _Float16* l) {
    __builtin_amdgcn_global_load_lds(
        (const __attribute__((address_space(1))) void*)g,
        (__attribute__((address_space(3))) void*)l, 16, 0, 0);
}

// ---------------------------------------------------------------------------
// fp32 -> f16 conversion
// ---------------------------------------------------------------------------
__global__ __launch_bounds__(256) void f32_to_f16(
    const float* __restrict__ in, _Float16* __restrict__ out, int n8)
{
    int i = blockIdx.x * 256 + threadIdx.x;
    if (i >= n8) return;
    float4 a = ((const float4*)in)[2 * i];
    float4 b = ((const float4*)in)[2 * i + 1];
    half8_t h;
    h[0] = (_Float16)a.x; h[1] = (_Float16)a.y; h[2] = (_Float16)a.z; h[3] = (_Float16)a.w;
    h[4] = (_Float16)b.x; h[5] = (_Float16)b.y; h[6] = (_Float16)b.z; h[7] = (_Float16)b.w;
    ((half8_t*)out)[i] = h;
}

// ---------------------------------------------------------------------------
// Zero q_h pad lanes (d=72..95): per chunk halves [4608, 6144)
// ---------------------------------------------------------------------------
__global__ __launch_bounds__(256) void zero_qpad(_Float16* __restrict__ qh)
{
    int i = blockIdx.x * 256 + threadIdx.x;   // 196608 total half8s
    int chunk = i / 192, within = i - chunk * 192;
    half8_t z = {};
    *(half8_t*)(qh + (size_t)chunk * CHUNK_HALVES + 4608 + within * 8) = z;
}

// ---------------------------------------------------------------------------
// enc_k / enc_v (B,H,N,72 f32) -> blocked f16 (k layout / vt layout)
// ---------------------------------------------------------------------------
__global__ __launch_bounds__(256) void enc_convert(
    const float* __restrict__ ek, const float* __restrict__ ev,
    _Float16* __restrict__ ekh, _Float16* __restrict__ evth)
{
    const int bh = blockIdx.y, nblk = blockIdx.x, t = threadIdx.x;
    const float* ksrc = ek + ((size_t)bh * PN + nblk * 64) * PHD;
    const float* vsrc = ev + ((size_t)bh * PN + nblk * 64) * PHD;
    _Float16* kdst = ekh  + ((size_t)bh * 16 + nblk) * CHUNK_HALVES;
    _Float16* vdst = evth + ((size_t)bh * 16 + nblk) * CHUNK_HALVES;
    for (int i = t; i < 64 * 18; i += 256) {
        int n = i / 18, d4 = (i % 18) * 4;
        float4 kv = *(const float4*)&ksrc[n * PHD + d4];
        float4 vv = *(const float4*)&vsrc[n * PHD + d4];
        float ka[4] = {kv.x, kv.y, kv.z, kv.w};
        float va[4] = {vv.x, vv.y, vv.z, vv.w};
#pragma unroll
        for (int kk = 0; kk < 4; ++kk) {
            int d = d4 + kk;
            kdst[(d >> 3) * 512 + n * 8 + (d & 7)] = (_Float16)ka[kk];
            vdst[(n >> 3) * 768 + d * 8 + (n & 7)] = (_Float16)va[kk];
        }
    }
}

// ---------------------------------------------------------------------------
// MFMA f16 GEMM, 128x128 tile, BK=64, grouped-swizzle 1D grid.
// MODE 0: QKV epilogue -> blocked f16 q/k/vt (q pre-scaled)
// MODE 1: proj epilogue -> f32 (M,C) + bias
// ---------------------------------------------------------------------------
template<int MODE>
__global__ __launch_bounds__(256) void gemm_mfma(
    const _Float16* __restrict__ A, const _Float16* __restrict__ Bm,
    const float* __restrict__ bias,
    _Float16* __restrict__ qh, _Float16* __restrict__ kh,
    _Float16* __restrict__ vth, float* __restrict__ out, int c_tiles)
{
    const int t    = threadIdx.x;
    const int lane = t & 63;
    const int w    = t >> 6;
    const int wm   = w >> 1, wn = w & 1;
    const int lrow = lane & 15, quad = lane >> 4;

    const int per_group = c_tiles * 8;
    const int g  = blockIdx.x / per_group;
    const int r_ = blockIdx.x - g * per_group;
    const int m0 = (g * 8 + (r_ & 7)) * 128;
    const int c0 = (r_ >> 3) * 128;

    __shared__ _Float16 As[8192];
    __shared__ _Float16 Bs[8192];

    int rowS[4], koff[4], ldsOff[4];
#pragma unroll
    for (int i = 0; i < 4; ++i) {
        int idx = w * 256 + i * 64 + lane;
        int kt2 = idx >> 9, qq = (idx >> 7) & 3;
        rowS[i]   = idx & 127;
        koff[i]   = kt2 * 32 + qq * 8;
        ldsOff[i] = idx * 8;
    }

    const _Float16* aBase = A  + (size_t)m0 * K_DIM;
    const _Float16* bBase = Bm + (size_t)c0 * K_DIM;

    float4v acc[4][4];
#pragma unroll
    for (int ti = 0; ti < 4; ++ti)
#pragma unroll
        for (int tj = 0; tj < 4; ++tj)
            acc[ti][tj] = (float4v){0.f, 0.f, 0.f, 0.f};

    for (int kb = 0; kb < K_DIM; kb += 64) {
        __syncthreads();
#pragma unroll
        for (int i = 0; i < 4; ++i) {
            load16_lds(aBase + (size_t)rowS[i] * K_DIM + kb + koff[i], &As[ldsOff[i]]);
            load16_lds(bBase + (size_t)rowS[i] * K_DIM + kb + koff[i], &Bs[ldsOff[i]]);
        }
        __syncthreads();
#pragma unroll
        for (int s = 0; s < 2; ++s) {
            half8_t af[4], bf[4];
#pragma unroll
            for (int ti = 0; ti < 4; ++ti)
                af[ti] = *(const half8_t*)&As[(((s * 4 + quad) * 128) + wm * 64 + ti * 16 + lrow) * 8];
#pragma unroll
            for (int tj = 0; tj < 4; ++tj)
                bf[tj] = *(const half8_t*)&Bs[(((s * 4 + quad) * 128) + wn * 64 + tj * 16 + lrow) * 8];
#pragma unroll
            for (int ti = 0; ti < 4; ++ti)
#pragma unroll
                for (int tj = 0; tj < 4; ++tj)
                    acc[ti][tj] = __builtin_amdgcn_mfma_f32_16x16x32_f16(
                        af[ti], bf[tj], acc[ti][tj], 0, 0, 0);
        }
    }

    if (MODE == 0) {
        const float scale = 0.11785113019775792f; // 72^-0.5
#pragma unroll
        for (int tj = 0; tj < 4; ++tj) {
            int c = c0 + wn * 64 + tj * 16 + lrow;
            float bv = bias[c];
            int jq  = c / PC;
            int rem = c - jq * PC;
            int h   = rem / PHD;
            int d   = rem - h * PHD;
#pragma unroll
            for (int ti = 0; ti < 4; ++ti)
#pragma unroll
                for (int r = 0; r < 4; ++r) {
                    int m = m0 + wm * 64 + ti * 16 + quad * 4 + r;
                    int b = m >> 10, n = m & 1023;
                    int bh = b * PH + h;
                    size_t chunk = ((size_t)bh * 16 + (n >> 6)) * CHUNK_HALVES;
                    float val = acc[ti][tj][r] + bv;
                    if (jq == 0)
                        qh[chunk + (d >> 3) * 512 + (n & 63) * 8 + (d & 7)] = (_Float16)(val * scale);
                    else if (jq == 1)
                        kh[chunk + (d >> 3) * 512 + (n & 63) * 8 + (d & 7)] = (_Float16)val;
                    else
                        vth[chunk + ((n & 63) >> 3) * 768 + d * 8 + (n & 7)] = (_Float16)val;
                }
        }
    } else {
#pragma unroll
        for (int tj = 0; tj < 4; ++tj) {
            int c = c0 + wn * 64 + tj * 16 + lrow;
            float bv = bias[c];
#pragma unroll
            for (int ti = 0; ti < 4; ++ti)
#pragma unroll
                for (int r = 0; r < 4; ++r) {
                    int m = m0 + wm * 64 + ti * 16 + quad * 4 + r;
                    out[(size_t)m * PC + c] = acc[ti][tj][r] + bv;
                }
        }
    }
}

// ---------------------------------------------------------------------------
// One flash-attention chunk step: S = Q K^T, online softmax, O += P Vt.
// Wave-local P round-trip through Ps (1 KB/wave region).
// ---------------------------------------------------------------------------
__device__ __forceinline__ void attn_step(
    const _Float16* Qs, const _Float16* Ks, const _Float16* Vts, _Float16* Ps,
    float4v* O, float* m_run, float* l_run, int w, int ln, int quad)
{
    float4v accS[4];
#pragma unroll
    for (int ct = 0; ct < 4; ++ct) accS[ct] = (float4v){0.f, 0.f, 0.f, 0.f};
#pragma unroll
    for (int ks = 0; ks < 3; ++ks) {
        half8_t af = *(const half8_t*)&Qs[(((ks * 4 + quad) * 64) + w * 16 + ln) * 8];
#pragma unroll
        for (int ct = 0; ct < 4; ++ct) {
            half8_t bf = *(const half8_t*)&Ks[(((ks * 4 + quad) * 64) + ct * 16 + ln) * 8];
            accS[ct] = __builtin_amdgcn_mfma_f32_16x16x32_f16(af, bf, accS[ct], 0, 0, 0);
        }
    }

    float alpha[4], lsum[4];
#pragma unroll
    for (int r = 0; r < 4; ++r) {
        float mx = fmaxf(fmaxf(accS[0][r], accS[1][r]), fmaxf(accS[2][r], accS[3][r]));
#pragma unroll
        for (int mask = 1; mask < 16; mask <<= 1)
            mx = fmaxf(mx, __shfl_xor(mx, mask));
        float m_new = fmaxf(m_run[r], mx);
        alpha[r] = __expf(m_run[r] - m_new);
        m_run[r] = m_new;
        lsum[r] = 0.f;
    }
#pragma unroll
    for (int ct = 0; ct < 4; ++ct) {
        int kcol = ct * 16 + ln;
        int pbase = (w * 8 + (kcol >> 3)) * 128 + (kcol & 7);
#pragma unroll
        for (int r = 0; r < 4; ++r) {
            float p = __expf(accS[ct][r] - m_run[r]);
            lsum[r] += p;
            Ps[pbase + (quad * 4 + r) * 8] = (_Float16)p;
        }
    }
#pragma unroll
    for (int r = 0; r < 4; ++r) {
#pragma unroll
        for (int mask = 1; mask < 16; mask <<= 1)
            lsum[r] += __shfl_xor(lsum[r], mask);
        l_run[r] = l_run[r] * alpha[r] + lsum[r];
    }
#pragma unroll
    for (int ct = 0; ct < 5; ++ct)
#pragma unroll
        for (int r = 0; r < 4; ++r) O[ct][r] *= alpha[r];

#pragma unroll
    for (int ks = 0; ks < 2; ++ks) {
        half8_t pa = *(const half8_t*)&Ps[((w * 8 + ks * 4 + quad) * 16 + ln) * 8];
#pragma unroll
        for (int ct = 0; ct < 5; ++ct) {
            half8_t vf = *(const half8_t*)&Vts[(((ks * 4 + quad) * 96) + ct * 16 + ln) * 8];
            O[ct] = __builtin_amdgcn_mfma_f32_16x16x32_f16(pa, vf, O[ct], 0, 0, 0);
        }
    }
}

// ---------------------------------------------------------------------------
// Fused dual-pass flash attention, cross-pass software pipelined:
//   issue enc(kt)->B ; compute own(kt) on A ; barrier
//   issue own(kt+1)->A ; compute enc(kt) on B ; barrier
// Each DMA overlaps a full compute phase before the barrier drain.
// XCD-affinity swizzle keeps each head's K/V on one XCD's L2.
// ---------------------------------------------------------------------------
__global__ __launch_bounds__(256) void attn_fused(
    const _Float16* __restrict__ qh, const _Float16* __restrict__ kh,
    const _Float16* __restrict__ vth,
    const _Float16* __restrict__ ekh, const _Float16* __restrict__ evth,
    _Float16* __restrict__ xouth, float* __restrict__ loss_out)
{
    const int t = threadIdx.x;
    const int lane = t & 63;
    const int w = t >> 6;
    const int ln = lane & 15;
    const int quad = lane >> 4;

    const int lid  = blockIdx.x;             // 1024 blocks
    const int bh   = (lid & 7) * 8 + ((lid >> 3) >> 4);
    const int nblk = (lid >> 3) & 15;

    __shared__ _Float16 Qs[CHUNK_HALVES];
    __shared__ _Float16 KsA[CHUNK_HALVES];
    __shared__ _Float16 VsA[CHUNK_HALVES];
    __shared__ _Float16 KsB[CHUNK_HALVES];
    __shared__ _Float16 VsB[CHUNK_HALVES];
    __shared__ _Float16 Ps[4096];   // per-wave [8 kq][16 rows][8]
    __shared__ float red[256];

    const _Float16* qc = qh + ((size_t)bh * 16 + nblk) * CHUNK_HALVES;
    const _Float16* kbo = kh   + (size_t)bh * HEAD_HALVES;
    const _Float16* vbo = vth  + (size_t)bh * HEAD_HALVES;
    const _Float16* kbe = ekh  + (size_t)bh * HEAD_HALVES;
    const _Float16* vbe = evth + (size_t)bh * HEAD_HALVES;

    // stage Q + own chunk 0
#pragma unroll
    for (int i = 0; i < 3; ++i) {
        int u = i * 256 + t;
        load16_lds(qc + u * 8, &Qs[u * 8]);
        load16_lds(kbo + u * 8, &KsA[u * 8]);
        load16_lds(vbo + u * 8, &VsA[u * 8]);
    }
    __syncthreads();   // Q + A ready

    float4v Oo[5], Oe[5];
#pragma unroll
    for (int ct = 0; ct < 5; ++ct) {
        Oo[ct] = (float4v){0.f, 0.f, 0.f, 0.f};
        Oe[ct] = (float4v){0.f, 0.f, 0.f, 0.f};
    }
    float m_o[4] = {-1e30f, -1e30f, -1e30f, -1e30f};
    float l_o[4] = {0.f, 0.f, 0.f, 0.f};
    float m_e[4] = {-1e30f, -1e30f, -1e30f, -1e30f};
    float l_e[4] = {0.f, 0.f, 0.f, 0.f};

    for (int kt = 0; kt < 16; ++kt) {
        // prefetch enc(kt) into B while computing own(kt) on A
        {
            const _Float16* kc = kbe + (size_t)kt * CHUNK_HALVES;
            const _Float16* vc = vbe + (size_t)kt * CHUNK_HALVES;
#pragma unroll
            for (int i = 0; i < 3; ++i) {
                int u = i * 256 + t;
                load16_lds(kc + u * 8, &KsB[u * 8]);
                load16_lds(vc + u * 8, &VsB[u * 8]);
            }
        }
        attn_step(Qs, KsA, VsA, Ps, Oo, m_o, l_o, w, ln, quad);
        __syncthreads();   // drains B's DMA; all waves done with A

        // prefetch own(kt+1) into A while computing enc(kt) on B
        if (kt < 15) {
            const _Float16* kc = kbo + (size_t)(kt + 1) * CHUNK_HALVES;
            const _Float16* vc = vbo + (size_t)(kt + 1) * CHUNK_HALVES;
#pragma unroll
            for (int i = 0; i < 3; ++i) {
                int u = i * 256 + t;
                load16_lds(kc + u * 8, &KsA[u * 8]);
                load16_lds(vc + u * 8, &VsA[u * 8]);
            }
        }
        attn_step(Qs, KsB, VsB, Ps, Oe, m_e, l_e, w, ln, quad);
        __syncthreads();   // drains A's DMA; all waves done with B
    }

    float inv_o[4], inv_e[4];
#pragma unroll
    for (int r = 0; r < 4; ++r) {
        inv_o[r] = 1.0f / l_o[r];
        inv_e[r] = 1.0f / l_e[r];
    }

    const int b = bh >> 4, h = bh & 15;
    const int nrow = nblk * 64 + w * 16 + quad * 4;

    float lacc = 0.f;
#pragma unroll
    for (int ct = 0; ct < 5; ++ct) {
        int d = ct * 16 + ln;
        if (d < PHD) {
#pragma unroll
            for (int r = 0; r < 4; ++r) {
                float own = Oo[ct][r] * inv_o[r];
                size_t idx = ((size_t)(b * PN + nrow + r)) * PC + h * PHD + d;
                xouth[idx] = (_Float16)own;
                float df = own - Oe[ct][r] * inv_e[r];
                lacc += df * df;
            }
        }
    }

    red[t] = lacc;
    __syncthreads();
    for (int off = 128; off > 0; off >>= 1) {
        if (t < off) red[t] += red[t + off];
        __syncthreads();
    }
    if (t == 0) atomicAdd(loss_out, red[0] * (1.0f / (float)OUT_ELEMS));
}

// ---------------------------------------------------------------------------
extern "C" void kernel_launch(void* const* d_in, const int* in_sizes, int n_in,
                              void* d_out, int out_size, void* d_ws, size_t ws_size,
                              hipStream_t stream)
{
    const float* x      = (const float*)d_in[0];
    const float* enc_k  = (const float*)d_in[1];
    const float* enc_v  = (const float*)d_in[2];
    const float* qkv_w  = (const float*)d_in[3];
    const float* qkv_b  = (const float*)d_in[4];
    const float* proj_w = (const float*)d_in[5];
    const float* proj_b = (const float*)d_in[6];

    float* out = (float*)d_out;

    _Float16* x_h     = (_Float16*)d_ws;
    _Float16* qkvw_h  = x_h + OUT_ELEMS;
    _Float16* projw_h = qkvw_h + (size_t)QKV_COLS * PC;
    _Float16* xout_h  = projw_h + (size_t)PC * PC;
    _Float16* q_h     = xout_h + OUT_ELEMS;
    _Float16* k_h     = q_h  + BUF_HALVES;
    _Float16* vt_h    = k_h  + BUF_HALVES;
    _Float16* ek_h    = vt_h + BUF_HALVES;
    _Float16* evt_h   = ek_h + BUF_HALVES;

    const int n8_x  = (int)(OUT_ELEMS / 8);
    const int n8_qw = QKV_COLS * PC / 8;
    const int n8_pw = PC * PC / 8;

    // 0. zero loss slot + q pads
    hipMemsetAsync(out + OUT_ELEMS, 0, sizeof(float), stream);
    zero_qpad<<<768, 256, 0, stream>>>(q_h);

    // conversions
    f32_to_f16<<<(n8_x  + 255) / 256, 256, 0, stream>>>(x,      x_h,     n8_x);
    f32_to_f16<<<(n8_qw + 255) / 256, 256, 0, stream>>>(qkv_w,  qkvw_h,  n8_qw);
    f32_to_f16<<<(n8_pw + 255) / 256, 256, 0, stream>>>(proj_w, projw_h, n8_pw);
    enc_convert<<<dim3(16, BH), 256, 0, stream>>>(enc_k, enc_v, ek_h, evt_h);

    // 1. QKV projection -> blocked f16 q/k/vt (q pre-scaled); 27 c-tiles
    gemm_mfma<0><<<(QKV_COLS / 128) * ((PB * PN) / 128), 256, 0, stream>>>(
        x_h, qkvw_h, qkv_b, q_h, k_h, vt_h, nullptr, QKV_COLS / 128);

    // 2. Fused pipelined own+enc attention -> xout_h + loss into out[OUT_ELEMS]
    attn_fused<<<16 * BH, 256, 0, stream>>>(
        q_h, k_h, vt_h, ek_h, evt_h, xout_h, out + OUT_ELEMS);

    // 3. Output projection; 9 c-tiles
    gemm_mfma<1><<<(PC / 128) * ((PB * PN) / 128), 256, 0, stream>>>(
        xout_h, projw_h, proj_b, nullptr, nullptr, nullptr, out, PC / 128);
}

// Round 6
// 356.696 us; speedup vs baseline: 5.7213x; 1.1151x over previous
//
#include <hip/hip_runtime.h>
#include <hip/hip_bf16.h>

// Problem constants: B=4, N=1024, C=1152, H=16, hd=72
#define PB 4
#define PN 1024
#define PC 1152
#define PH 16
#define PHD 72
#define BH 64
#define QKV_COLS 3456
#define OUT_ELEMS ((size_t)PB*PN*PC)   // 4718592
#define K_DIM 1152

// Blocked f16 layouts (per (bh, 64-row chunk), 6144 halves = 12288 B):
//  q/k:  [dq(12)][row(64)][8]   element (n,d) -> (d>>3)*512 + (n&63)*8 + (d&7)
//  vt :  [kq(8)][hd(96)][8]     element (n,d) -> ((n&63)>>3)*768 + d*8 + (n&7)
#define CHUNK_HALVES 6144
#define HEAD_HALVES (16*CHUNK_HALVES)       // 98304
#define BUF_HALVES ((size_t)BH*HEAD_HALVES) // 6291456 per buffer

typedef _Float16 half8_t __attribute__((ext_vector_type(8)));
typedef _Float16 half4_t __attribute__((ext_vector_type(4)));
typedef float float4v __attribute__((ext_vector_type(4)));

__device__ __forceinline__ void load16_lds(const _Float16* g, _Float16* l) {
    __builtin_amdgcn_global_load_lds(
        (const __attribute__((address_space(1))) void*)g,
        (__attribute__((address_space(3))) void*)l, 16, 0, 0);
}

// ---------------------------------------------------------------------------
// fp32 -> f16 conversion
// ---------------------------------------------------------------------------
__global__ __launch_bounds__(256) void f32_to_f16(
    const float* __restrict__ in, _Float16* __restrict__ out, int n8)
{
    int i = blockIdx.x * 256 + threadIdx.x;
    if (i >= n8) return;
    float4 a = ((const float4*)in)[2 * i];
    float4 b = ((const float4*)in)[2 * i + 1];
    half8_t h;
    h[0] = (_Float16)a.x; h[1] = (_Float16)a.y; h[2] = (_Float16)a.z; h[3] = (_Float16)a.w;
    h[4] = (_Float16)b.x; h[5] = (_Float16)b.y; h[6] = (_Float16)b.z; h[7] = (_Float16)b.w;
    ((half8_t*)out)[i] = h;
}

// ---------------------------------------------------------------------------
// Zero q_h pad lanes (d=72..95): per chunk halves [4608, 6144)
// ---------------------------------------------------------------------------
__global__ __launch_bounds__(256) void zero_qpad(_Float16* __restrict__ qh)
{
    int i = blockIdx.x * 256 + threadIdx.x;   // 196608 total half8s
    int chunk = i / 192, within = i - chunk * 192;
    half8_t z = {};
    *(half8_t*)(qh + (size_t)chunk * CHUNK_HALVES + 4608 + within * 8) = z;
}

// ---------------------------------------------------------------------------
// enc_k / enc_v (B,H,N,72 f32) -> blocked f16 (k layout / vt layout)
// ---------------------------------------------------------------------------
__global__ __launch_bounds__(256) void enc_convert(
    const float* __restrict__ ek, const float* __restrict__ ev,
    _Float16* __restrict__ ekh, _Float16* __restrict__ evth)
{
    const int bh = blockIdx.y, nblk = blockIdx.x, t = threadIdx.x;
    const float* ksrc = ek + ((size_t)bh * PN + nblk * 64) * PHD;
    const float* vsrc = ev + ((size_t)bh * PN + nblk * 64) * PHD;
    _Float16* kdst = ekh  + ((size_t)bh * 16 + nblk) * CHUNK_HALVES;
    _Float16* vdst = evth + ((size_t)bh * 16 + nblk) * CHUNK_HALVES;
    for (int i = t; i < 64 * 18; i += 256) {
        int n = i / 18, d4 = (i % 18) * 4;
        float4 kv = *(const float4*)&ksrc[n * PHD + d4];
        float4 vv = *(const float4*)&vsrc[n * PHD + d4];
        float ka[4] = {kv.x, kv.y, kv.z, kv.w};
        float va[4] = {vv.x, vv.y, vv.z, vv.w};
#pragma unroll
        for (int kk = 0; kk < 4; ++kk) {
            int d = d4 + kk;
            kdst[(d >> 3) * 512 + n * 8 + (d & 7)] = (_Float16)ka[kk];
            vdst[(n >> 3) * 768 + d * 8 + (n & 7)] = (_Float16)va[kk];
        }
    }
}

// ---------------------------------------------------------------------------
// MFMA f16 GEMM, 128x128 tile, BK=64, grouped-swizzle 1D grid.
// MODE 0: QKV epilogue -> blocked f16 q/k/vt (q pre-scaled)
// MODE 1: proj epilogue -> f32 (M,C) + bias
// ---------------------------------------------------------------------------
template<int MODE>
__global__ __launch_bounds__(256) void gemm_mfma(
    const _Float16* __restrict__ A, const _Float16* __restrict__ Bm,
    const float* __restrict__ bias,
    _Float16* __restrict__ qh, _Float16* __restrict__ kh,
    _Float16* __restrict__ vth, float* __restrict__ out, int c_tiles)
{
    const int t    = threadIdx.x;
    const int lane = t & 63;
    const int w    = t >> 6;
    const int wm   = w >> 1, wn = w & 1;
    const int lrow = lane & 15, quad = lane >> 4;

    const int per_group = c_tiles * 8;
    const int g  = blockIdx.x / per_group;
    const int r_ = blockIdx.x - g * per_group;
    const int m0 = (g * 8 + (r_ & 7)) * 128;
    const int c0 = (r_ >> 3) * 128;

    __shared__ _Float16 As[8192];
    __shared__ _Float16 Bs[8192];

    int rowS[4], koff[4], ldsOff[4];
#pragma unroll
    for (int i = 0; i < 4; ++i) {
        int idx = w * 256 + i * 64 + lane;
        int kt2 = idx >> 9, qq = (idx >> 7) & 3;
        rowS[i]   = idx & 127;
        koff[i]   = kt2 * 32 + qq * 8;
        ldsOff[i] = idx * 8;
    }

    const _Float16* aBase = A  + (size_t)m0 * K_DIM;
    const _Float16* bBase = Bm + (size_t)c0 * K_DIM;

    float4v acc[4][4];
#pragma unroll
    for (int ti = 0; ti < 4; ++ti)
#pragma unroll
        for (int tj = 0; tj < 4; ++tj)
            acc[ti][tj] = (float4v){0.f, 0.f, 0.f, 0.f};

    for (int kb = 0; kb < K_DIM; kb += 64) {
        __syncthreads();
#pragma unroll
        for (int i = 0; i < 4; ++i) {
            load16_lds(aBase + (size_t)rowS[i] * K_DIM + kb + koff[i], &As[ldsOff[i]]);
            load16_lds(bBase + (size_t)rowS[i] * K_DIM + kb + koff[i], &Bs[ldsOff[i]]);
        }
        __syncthreads();
#pragma unroll
        for (int s = 0; s < 2; ++s) {
            half8_t af[4], bf[4];
#pragma unroll
            for (int ti = 0; ti < 4; ++ti)
                af[ti] = *(const half8_t*)&As[(((s * 4 + quad) * 128) + wm * 64 + ti * 16 + lrow) * 8];
#pragma unroll
            for (int tj = 0; tj < 4; ++tj)
                bf[tj] = *(const half8_t*)&Bs[(((s * 4 + quad) * 128) + wn * 64 + tj * 16 + lrow) * 8];
#pragma unroll
            for (int ti = 0; ti < 4; ++ti)
#pragma unroll
                for (int tj = 0; tj < 4; ++tj)
                    acc[ti][tj] = __builtin_amdgcn_mfma_f32_16x16x32_f16(
                        af[ti], bf[tj], acc[ti][tj], 0, 0, 0);
        }
    }

    if (MODE == 0) {
        const float scale = 0.11785113019775792f; // 72^-0.5
#pragma unroll
        for (int tj = 0; tj < 4; ++tj) {
            int c = c0 + wn * 64 + tj * 16 + lrow;
            float bv = bias[c];
            int jq  = c / PC;
            int rem = c - jq * PC;
            int h   = rem / PHD;
            int d   = rem - h * PHD;
#pragma unroll
            for (int ti = 0; ti < 4; ++ti)
#pragma unroll
                for (int r = 0; r < 4; ++r) {
                    int m = m0 + wm * 64 + ti * 16 + quad * 4 + r;
                    int b = m >> 10, n = m & 1023;
                    int bh = b * PH + h;
                    size_t chunk = ((size_t)bh * 16 + (n >> 6)) * CHUNK_HALVES;
                    float val = acc[ti][tj][r] + bv;
                    if (jq == 0)
                        qh[chunk + (d >> 3) * 512 + (n & 63) * 8 + (d & 7)] = (_Float16)(val * scale);
                    else if (jq == 1)
                        kh[chunk + (d >> 3) * 512 + (n & 63) * 8 + (d & 7)] = (_Float16)val;
                    else
                        vth[chunk + ((n & 63) >> 3) * 768 + d * 8 + (n & 7)] = (_Float16)val;
                }
        }
    } else {
#pragma unroll
        for (int tj = 0; tj < 4; ++tj) {
            int c = c0 + wn * 64 + tj * 16 + lrow;
            float bv = bias[c];
#pragma unroll
            for (int ti = 0; ti < 4; ++ti)
#pragma unroll
                for (int r = 0; r < 4; ++r) {
                    int m = m0 + wm * 64 + ti * 16 + quad * 4 + r;
                    out[(size_t)m * PC + c] = acc[ti][tj][r] + bv;
                }
        }
    }
}

// ---------------------------------------------------------------------------
// One transposed flash-attention step:
//   S^T = K Q^T (C-layout: lane ln owns Q-row ln, 16 kidx per lane)
//   lane-local softmax (2 shfls/row-reduction across quads only)
//   P packed to B-operand layout via 4 ds_write_b64, then O^T += V^T P^T.
// Pw = per-wave 1024-half region.
// ---------------------------------------------------------------------------
__device__ __forceinline__ void attn_step(
    const _Float16* Qs, const _Float16* Ks, const _Float16* Vts, _Float16* Pw,
    float4v* O, float& m_run, float& l_run, int w, int ln, int quad)
{
    float4v accS[4];
#pragma unroll
    for (int ct = 0; ct < 4; ++ct) accS[ct] = (float4v){0.f, 0.f, 0.f, 0.f};
#pragma unroll
    for (int ks = 0; ks < 3; ++ks) {
        half8_t qf = *(const half8_t*)&Qs[(((ks * 4 + quad) * 64) + w * 16 + ln) * 8];
#pragma unroll
        for (int ct = 0; ct < 4; ++ct) {
            half8_t kf = *(const half8_t*)&Ks[(((ks * 4 + quad) * 64) + ct * 16 + ln) * 8];
            accS[ct] = __builtin_amdgcn_mfma_f32_16x16x32_f16(kf, qf, accS[ct], 0, 0, 0);
        }
    }

    // row max over this lane's 16 scores, then across quads (lanes ln+16k)
    float mx = -1e30f;
#pragma unroll
    for (int ct = 0; ct < 4; ++ct)
#pragma unroll
        for (int r = 0; r < 4; ++r) mx = fmaxf(mx, accS[ct][r]);
    mx = fmaxf(mx, __shfl_xor(mx, 16));
    mx = fmaxf(mx, __shfl_xor(mx, 32));
    float m_new = fmaxf(m_run, mx);
    float alpha = __expf(m_run - m_new);
    m_run = m_new;

    // exp, pack, write P^T in B-operand layout: half addr (k>>3)*128 + ln*8 + (k&7)
    float lsum = 0.f;
    const int pbase = (quad >> 1) * 128 + ln * 8 + (quad & 1) * 4;
#pragma unroll
    for (int ct = 0; ct < 4; ++ct) {
        half4_t pk;
#pragma unroll
        for (int r = 0; r < 4; ++r) {
            float p = __expf(accS[ct][r] - m_new);
            lsum += p;
            pk[r] = (_Float16)p;
        }
        *(half4_t*)&Pw[pbase + ct * 256] = pk;
    }
    lsum += __shfl_xor(lsum, 16);
    lsum += __shfl_xor(lsum, 32);
    l_run = l_run * alpha + lsum;

#pragma unroll
    for (int ct = 0; ct < 5; ++ct) O[ct] *= alpha;

    // O^T += V^T P^T : A = V^T frag, B = P^T frag
#pragma unroll
    for (int ks = 0; ks < 2; ++ks) {
        half8_t pf = *(const half8_t*)&Pw[(ks * 4 + quad) * 128 + ln * 8];
#pragma unroll
        for (int ct = 0; ct < 5; ++ct) {
            half8_t vf = *(const half8_t*)&Vts[(((ks * 4 + quad) * 96) + ct * 16 + ln) * 8];
            O[ct] = __builtin_amdgcn_mfma_f32_16x16x32_f16(vf, pf, O[ct], 0, 0, 0);
        }
    }
}

// ---------------------------------------------------------------------------
// Fused dual-pass flash attention, cross-pass software pipelined:
//   issue enc(kt)->B ; compute own(kt) on A ; barrier
//   issue own(kt+1)->A ; compute enc(kt) on B ; barrier
// O held transposed (O^T), softmax state per-lane (qrow = lane&15).
// XCD-affinity swizzle keeps each head's K/V on one XCD's L2.
// ---------------------------------------------------------------------------
__global__ __launch_bounds__(256) void attn_fused(
    const _Float16* __restrict__ qh, const _Float16* __restrict__ kh,
    const _Float16* __restrict__ vth,
    const _Float16* __restrict__ ekh, const _Float16* __restrict__ evth,
    _Float16* __restrict__ xouth, float* __restrict__ loss_out)
{
    const int t = threadIdx.x;
    const int lane = t & 63;
    const int w = t >> 6;
    const int ln = lane & 15;
    const int quad = lane >> 4;

    const int lid  = blockIdx.x;             // 1024 blocks
    const int bh   = (lid & 7) * 8 + ((lid >> 3) >> 4);
    const int nblk = (lid >> 3) & 15;

    __shared__ _Float16 Qs[CHUNK_HALVES];
    __shared__ _Float16 KsA[CHUNK_HALVES];
    __shared__ _Float16 VsA[CHUNK_HALVES];
    __shared__ _Float16 KsB[CHUNK_HALVES];
    __shared__ _Float16 VsB[CHUNK_HALVES];
    __shared__ _Float16 Ps[4096];   // per-wave 1024-half P^T region
    __shared__ float red[256];

    _Float16* Pw = Ps + w * 1024;

    const _Float16* qc = qh + ((size_t)bh * 16 + nblk) * CHUNK_HALVES;
    const _Float16* kbo = kh   + (size_t)bh * HEAD_HALVES;
    const _Float16* vbo = vth  + (size_t)bh * HEAD_HALVES;
    const _Float16* kbe = ekh  + (size_t)bh * HEAD_HALVES;
    const _Float16* vbe = evth + (size_t)bh * HEAD_HALVES;

    // stage Q + own chunk 0
#pragma unroll
    for (int i = 0; i < 3; ++i) {
        int u = i * 256 + t;
        load16_lds(qc + u * 8, &Qs[u * 8]);
        load16_lds(kbo + u * 8, &KsA[u * 8]);
        load16_lds(vbo + u * 8, &VsA[u * 8]);
    }
    __syncthreads();   // Q + A ready

    float4v Oo[5], Oe[5];
#pragma unroll
    for (int ct = 0; ct < 5; ++ct) {
        Oo[ct] = (float4v){0.f, 0.f, 0.f, 0.f};
        Oe[ct] = (float4v){0.f, 0.f, 0.f, 0.f};
    }
    float m_o = -1e30f, l_o = 0.f;
    float m_e = -1e30f, l_e = 0.f;

    for (int kt = 0; kt < 16; ++kt) {
        // prefetch enc(kt) into B while computing own(kt) on A
        {
            const _Float16* kc = kbe + (size_t)kt * CHUNK_HALVES;
            const _Float16* vc = vbe + (size_t)kt * CHUNK_HALVES;
#pragma unroll
            for (int i = 0; i < 3; ++i) {
                int u = i * 256 + t;
                load16_lds(kc + u * 8, &KsB[u * 8]);
                load16_lds(vc + u * 8, &VsB[u * 8]);
            }
        }
        attn_step(Qs, KsA, VsA, Pw, Oo, m_o, l_o, w, ln, quad);
        __syncthreads();   // drains B's DMA; all waves done with A

        // prefetch own(kt+1) into A while computing enc(kt) on B
        if (kt < 15) {
            const _Float16* kc = kbo + (size_t)(kt + 1) * CHUNK_HALVES;
            const _Float16* vc = vbo + (size_t)(kt + 1) * CHUNK_HALVES;
#pragma unroll
            for (int i = 0; i < 3; ++i) {
                int u = i * 256 + t;
                load16_lds(kc + u * 8, &KsA[u * 8]);
                load16_lds(vc + u * 8, &VsA[u * 8]);
            }
        }
        attn_step(Qs, KsB, VsB, Pw, Oe, m_e, l_e, w, ln, quad);
        __syncthreads();   // drains A's DMA; all waves done with B
    }

    const float inv_o = 1.0f / l_o;
    const float inv_e = 1.0f / l_e;

    const int b = bh >> 4, h = bh & 15;
    const int nrow = nblk * 64 + w * 16 + ln;   // this lane's Q-row

    float lacc = 0.f;
    const size_t rowbase = (size_t)(b * PN + nrow) * PC + h * PHD;
#pragma unroll
    for (int ct = 0; ct < 5; ++ct) {
        int d0 = ct * 16 + quad * 4;
        if (d0 < PHD) {                  // ct=4: only quads 0,1 valid
            half4_t oh;
#pragma unroll
            for (int r = 0; r < 4; ++r) {
                float own = Oo[ct][r] * inv_o;
                oh[r] = (_Float16)own;
                float df = own - Oe[ct][r] * inv_e;
                lacc += df * df;
            }
            *(half4_t*)&xouth[rowbase + d0] = oh;   // 8B aligned
        }
    }

    red[t] = lacc;
    __syncthreads();
    for (int off = 128; off > 0; off >>= 1) {
        if (t < off) red[t] += red[t + off];
        __syncthreads();
    }
    if (t == 0) atomicAdd(loss_out, red[0] * (1.0f / (float)OUT_ELEMS));
}

// ---------------------------------------------------------------------------
extern "C" void kernel_launch(void* const* d_in, const int* in_sizes, int n_in,
                              void* d_out, int out_size, void* d_ws, size_t ws_size,
                              hipStream_t stream)
{
    const float* x      = (const float*)d_in[0];
    const float* enc_k  = (const float*)d_in[1];
    const float* enc_v  = (const float*)d_in[2];
    const float* qkv_w  = (const float*)d_in[3];
    const float* qkv_b  = (const float*)d_in[4];
    const float* proj_w = (const float*)d_in[5];
    const float* proj_b = (const float*)d_in[6];

    float* out = (float*)d_out;

    _Float16* x_h     = (_Float16*)d_ws;
    _Float16* qkvw_h  = x_h + OUT_ELEMS;
    _Float16* projw_h = qkvw_h + (size_t)QKV_COLS * PC;
    _Float16* xout_h  = projw_h + (size_t)PC * PC;
    _Float16* q_h     = xout_h + OUT_ELEMS;
    _Float16* k_h     = q_h  + BUF_HALVES;
    _Float16* vt_h    = k_h  + BUF_HALVES;
    _Float16* ek_h    = vt_h + BUF_HALVES;
    _Float16* evt_h   = ek_h + BUF_HALVES;

    const int n8_x  = (int)(OUT_ELEMS / 8);
    const int n8_qw = QKV_COLS * PC / 8;
    const int n8_pw = PC * PC / 8;

    // 0. zero loss slot + q pads
    hipMemsetAsync(out + OUT_ELEMS, 0, sizeof(float), stream);
    zero_qpad<<<768, 256, 0, stream>>>(q_h);

    // conversions
    f32_to_f16<<<(n8_x  + 255) / 256, 256, 0, stream>>>(x,      x_h,     n8_x);
    f32_to_f16<<<(n8_qw + 255) / 256, 256, 0, stream>>>(qkv_w,  qkvw_h,  n8_qw);
    f32_to_f16<<<(n8_pw + 255) / 256, 256, 0, stream>>>(proj_w, projw_h, n8_pw);
    enc_convert<<<dim3(16, BH), 256, 0, stream>>>(enc_k, enc_v, ek_h, evt_h);

    // 1. QKV projection -> blocked f16 q/k/vt (q pre-scaled); 27 c-tiles
    gemm_mfma<0><<<(QKV_COLS / 128) * ((PB * PN) / 128), 256, 0, stream>>>(
        x_h, qkvw_h, qkv_b, q_h, k_h, vt_h, nullptr, QKV_COLS / 128);

    // 2. Fused pipelined own+enc attention -> xout_h + loss into out[OUT_ELEMS]
    attn_fused<<<16 * BH, 256, 0, stream>>>(
        q_h, k_h, vt_h, ek_h, evt_h, xout_h, out + OUT_ELEMS);

    // 3. Output projection; 9 c-tiles
    gemm_mfma<1><<<(PC / 128) * ((PB * PN) / 128), 256, 0, stream>>>(
        xout_h, projw_h, proj_b, nullptr, nullptr, nullptr, out, PC / 128);
}

// Round 7
// 342.811 us; speedup vs baseline: 5.9531x; 1.0405x over previous
//
#include <hip/hip_runtime.h>
#include <hip/hip_bf16.h>

// Problem constants: B=4, N=1024, C=1152, H=16, hd=72
#define PB 4
#define PN 1024
#define PC 1152
#define PH 16
#define PHD 72
#define BH 64
#define QKV_COLS 3456
#define OUT_ELEMS ((size_t)PB*PN*PC)   // 4718592
#define K_DIM 1152

// Blocked f16 layouts (per (bh, 64-row chunk), 6144 halves = 12288 B):
//  q/k:  [dq(12)][row(64)][8]   element (n,d) -> (d>>3)*512 + (n&63)*8 + (d&7)
//  vt :  [kq(8)][hd(96)][8]     element (n,d) -> ((n&63)>>3)*768 + d*8 + (n&7)
#define CHUNK_HALVES 6144
#define HEAD_HALVES (16*CHUNK_HALVES)       // 98304
#define BUF_HALVES ((size_t)BH*HEAD_HALVES) // 6291456 per buffer

typedef _Float16 half8_t __attribute__((ext_vector_type(8)));
typedef _Float16 half4_t __attribute__((ext_vector_type(4)));
typedef float float4v __attribute__((ext_vector_type(4)));

// q pre-scale: hd^-0.5 * log2(e)  (softmax computed base-2, exactly equivalent)
#define QSCALE (0.11785113019775792f * 1.4426950408889634f)

__device__ __forceinline__ void load16_lds(const _Float16* g, _Float16* l) {
    __builtin_amdgcn_global_load_lds(
        (const __attribute__((address_space(1))) void*)g,
        (__attribute__((address_space(3))) void*)l, 16, 0, 0);
}

// ---------------------------------------------------------------------------
// fp32 -> f16 conversion
// ---------------------------------------------------------------------------
__global__ __launch_bounds__(256) void f32_to_f16(
    const float* __restrict__ in, _Float16* __restrict__ out, int n8)
{
    int i = blockIdx.x * 256 + threadIdx.x;
    if (i >= n8) return;
    float4 a = ((const float4*)in)[2 * i];
    float4 b = ((const float4*)in)[2 * i + 1];
    half8_t h;
    h[0] = (_Float16)a.x; h[1] = (_Float16)a.y; h[2] = (_Float16)a.z; h[3] = (_Float16)a.w;
    h[4] = (_Float16)b.x; h[5] = (_Float16)b.y; h[6] = (_Float16)b.z; h[7] = (_Float16)b.w;
    ((half8_t*)out)[i] = h;
}

// ---------------------------------------------------------------------------
// Zero q_h pad lanes (d=72..95): per chunk halves [4608, 6144)
// ---------------------------------------------------------------------------
__global__ __launch_bounds__(256) void zero_qpad(_Float16* __restrict__ qh)
{
    int i = blockIdx.x * 256 + threadIdx.x;   // 196608 total half8s
    int chunk = i / 192, within = i - chunk * 192;
    half8_t z = {};
    *(half8_t*)(qh + (size_t)chunk * CHUNK_HALVES + 4608 + within * 8) = z;
}

// ---------------------------------------------------------------------------
// enc_k / enc_v (B,H,N,72 f32) -> blocked f16 (k layout / vt layout)
// ---------------------------------------------------------------------------
__global__ __launch_bounds__(256) void enc_convert(
    const float* __restrict__ ek, const float* __restrict__ ev,
    _Float16* __restrict__ ekh, _Float16* __restrict__ evth)
{
    const int bh = blockIdx.y, nblk = blockIdx.x, t = threadIdx.x;
    const float* ksrc = ek + ((size_t)bh * PN + nblk * 64) * PHD;
    const float* vsrc = ev + ((size_t)bh * PN + nblk * 64) * PHD;
    _Float16* kdst = ekh  + ((size_t)bh * 16 + nblk) * CHUNK_HALVES;
    _Float16* vdst = evth + ((size_t)bh * 16 + nblk) * CHUNK_HALVES;
    for (int i = t; i < 64 * 18; i += 256) {
        int n = i / 18, d4 = (i % 18) * 4;
        float4 kv = *(const float4*)&ksrc[n * PHD + d4];
        float4 vv = *(const float4*)&vsrc[n * PHD + d4];
        float ka[4] = {kv.x, kv.y, kv.z, kv.w};
        float va[4] = {vv.x, vv.y, vv.z, vv.w};
#pragma unroll
        for (int kk = 0; kk < 4; ++kk) {
            int d = d4 + kk;
            kdst[(d >> 3) * 512 + n * 8 + (d & 7)] = (_Float16)ka[kk];
            vdst[(n >> 3) * 768 + d * 8 + (n & 7)] = (_Float16)va[kk];
        }
    }
}

// ---------------------------------------------------------------------------
// MFMA f16 GEMM, 128x128 tile, BK=64, grouped-swizzle 1D grid.
// Orientation: q/k tiles (c0 < 2*PC) and proj use C^T (operand swap) so each
// lane owns 4 consecutive cols -> vectorized stores. v tiles use normal C.
// MODE 0: QKV epilogue -> blocked f16 q/k/vt (q pre-scaled by QSCALE)
// MODE 1: proj epilogue -> f32 (M,C) + bias, float4 stores
// ---------------------------------------------------------------------------
template<int MODE>
__global__ __launch_bounds__(256) void gemm_mfma(
    const _Float16* __restrict__ A, const _Float16* __restrict__ Bm,
    const float* __restrict__ bias,
    _Float16* __restrict__ qh, _Float16* __restrict__ kh,
    _Float16* __restrict__ vth, float* __restrict__ out, int c_tiles)
{
    const int t    = threadIdx.x;
    const int lane = t & 63;
    const int w    = t >> 6;
    const int wm   = w >> 1, wn = w & 1;
    const int lrow = lane & 15, quad = lane >> 4;

    const int per_group = c_tiles * 8;
    const int g  = blockIdx.x / per_group;
    const int r_ = blockIdx.x - g * per_group;
    const int m0 = (g * 8 + (r_ & 7)) * 128;
    const int c0 = (r_ >> 3) * 128;

    const bool tr = (MODE == 1) || (c0 < 2 * PC);   // q/k + proj transposed

    __shared__ _Float16 As[8192];
    __shared__ _Float16 Bs[8192];

    int rowS[4], koff[4], ldsOff[4];
#pragma unroll
    for (int i = 0; i < 4; ++i) {
        int idx = w * 256 + i * 64 + lane;
        int kt2 = idx >> 9, qq = (idx >> 7) & 3;
        rowS[i]   = idx & 127;
        koff[i]   = kt2 * 32 + qq * 8;
        ldsOff[i] = idx * 8;
    }

    const _Float16* aBase = A  + (size_t)m0 * K_DIM;
    const _Float16* bBase = Bm + (size_t)c0 * K_DIM;

    float4v acc[4][4];
#pragma unroll
    for (int ti = 0; ti < 4; ++ti)
#pragma unroll
        for (int tj = 0; tj < 4; ++tj)
            acc[ti][tj] = (float4v){0.f, 0.f, 0.f, 0.f};

    for (int kb = 0; kb < K_DIM; kb += 64) {
        __syncthreads();
#pragma unroll
        for (int i = 0; i < 4; ++i) {
            load16_lds(aBase + (size_t)rowS[i] * K_DIM + kb + koff[i], &As[ldsOff[i]]);
            load16_lds(bBase + (size_t)rowS[i] * K_DIM + kb + koff[i], &Bs[ldsOff[i]]);
        }
        __syncthreads();
#pragma unroll
        for (int s = 0; s < 2; ++s) {
            half8_t af[4], bf[4];
#pragma unroll
            for (int ti = 0; ti < 4; ++ti)
                af[ti] = *(const half8_t*)&As[(((s * 4 + quad) * 128) + wm * 64 + ti * 16 + lrow) * 8];
#pragma unroll
            for (int tj = 0; tj < 4; ++tj)
                bf[tj] = *(const half8_t*)&Bs[(((s * 4 + quad) * 128) + wn * 64 + tj * 16 + lrow) * 8];
            if (tr) {
#pragma unroll
                for (int ti = 0; ti < 4; ++ti)
#pragma unroll
                    for (int tj = 0; tj < 4; ++tj)
                        acc[ti][tj] = __builtin_amdgcn_mfma_f32_16x16x32_f16(
                            bf[tj], af[ti], acc[ti][tj], 0, 0, 0);
            } else {
#pragma unroll
                for (int ti = 0; ti < 4; ++ti)
#pragma unroll
                    for (int tj = 0; tj < 4; ++tj)
                        acc[ti][tj] = __builtin_amdgcn_mfma_f32_16x16x32_f16(
                            af[ti], bf[tj], acc[ti][tj], 0, 0, 0);
            }
        }
    }

    if (MODE == 1) {
        // transposed: lane owns m = m0+wm*64+ti*16+lrow, c = cg..cg+3
#pragma unroll
        for (int tj = 0; tj < 4; ++tj) {
            int cg = c0 + wn * 64 + tj * 16 + quad * 4;
            float4v bv = *(const float4v*)&bias[cg];
#pragma unroll
            for (int ti = 0; ti < 4; ++ti) {
                int m = m0 + wm * 64 + ti * 16 + lrow;
                float4v o;
#pragma unroll
                for (int r = 0; r < 4; ++r) o[r] = acc[ti][tj][r] + bv[r];
                *(float4v*)&out[(size_t)m * PC + cg] = o;
            }
        }
    } else if (tr) {
        // q/k: lane owns n (fixed), d-group of 4 (never straddles a head)
        const int jq = c0 / PC;               // 0 = q, 1 = k (uniform per block)
        const float mulv = (jq == 0) ? QSCALE : 1.f;
        _Float16* dstp = (jq == 0) ? qh : kh;
#pragma unroll
        for (int tj = 0; tj < 4; ++tj) {
            int cg  = c0 + wn * 64 + tj * 16 + quad * 4;
            int rem = cg - jq * PC;
            int h   = rem / PHD;
            int ds  = rem - h * PHD;          // multiple of 4
            float4v bv = *(const float4v*)&bias[cg];
#pragma unroll
            for (int ti = 0; ti < 4; ++ti) {
                int m = m0 + wm * 64 + ti * 16 + lrow;
                int b = m >> 10, n = m & 1023;
                size_t chunk = ((size_t)(b * PH + h) * 16 + (n >> 6)) * CHUNK_HALVES;
                half4_t hv;
#pragma unroll
                for (int r = 0; r < 4; ++r)
                    hv[r] = (_Float16)((acc[ti][tj][r] + bv[r]) * mulv);
                *(half4_t*)&dstp[chunk + (ds >> 3) * 512 + (n & 63) * 8 + (ds & 7)] = hv;
            }
        }
    } else {
        // v: lane owns d (fixed), n-group of 4 -> contiguous in vt layout
#pragma unroll
        for (int tj = 0; tj < 4; ++tj) {
            int c   = c0 + wn * 64 + tj * 16 + lrow;
            int rem = c - 2 * PC;
            int h   = rem / PHD;
            int d   = rem - h * PHD;
            float bv = bias[c];
#pragma unroll
            for (int ti = 0; ti < 4; ++ti) {
                int mg = m0 + wm * 64 + ti * 16 + quad * 4;
                int b = mg >> 10, n = mg & 1023;
                size_t chunk = ((size_t)(b * PH + h) * 16 + (n >> 6)) * CHUNK_HALVES;
                half4_t hv;
#pragma unroll
                for (int r = 0; r < 4; ++r)
                    hv[r] = (_Float16)(acc[ti][tj][r] + bv);
                *(half4_t*)&vth[chunk + ((n & 63) >> 3) * 768 + d * 8 + (n & 7)] = hv;
            }
        }
    }
}

// ---------------------------------------------------------------------------
// One transposed flash-attention step (base-2 softmax; q pre-scaled by log2e):
//   S^T = K Q^T; lane-local softmax (2 shfls); P -> B-layout via 4 ds_write_b64;
//   O^T += V^T P^T.  Q-frags live in registers.
// ---------------------------------------------------------------------------
__device__ __forceinline__ void attn_step(
    const half8_t* qf, const _Float16* Ks, const _Float16* Vts, _Float16* Pw,
    float4v* O, float& m_run, float& l_run, int ln, int quad)
{
    float4v accS[4];
#pragma unroll
    for (int ct = 0; ct < 4; ++ct) accS[ct] = (float4v){0.f, 0.f, 0.f, 0.f};
#pragma unroll
    for (int ks = 0; ks < 3; ++ks) {
#pragma unroll
        for (int ct = 0; ct < 4; ++ct) {
            half8_t kf = *(const half8_t*)&Ks[(((ks * 4 + quad) * 64) + ct * 16 + ln) * 8];
            accS[ct] = __builtin_amdgcn_mfma_f32_16x16x32_f16(kf, qf[ks], accS[ct], 0, 0, 0);
        }
    }

    float mx = -1e30f;
#pragma unroll
    for (int ct = 0; ct < 4; ++ct)
#pragma unroll
        for (int r = 0; r < 4; ++r) mx = fmaxf(mx, accS[ct][r]);
    mx = fmaxf(mx, __shfl_xor(mx, 16));
    mx = fmaxf(mx, __shfl_xor(mx, 32));
    float m_new = fmaxf(m_run, mx);
    float alpha = exp2f(m_run - m_new);
    m_run = m_new;

    float lsum = 0.f;
    const int pbase = (quad >> 1) * 128 + ln * 8 + (quad & 1) * 4;
#pragma unroll
    for (int ct = 0; ct < 4; ++ct) {
        half4_t pk;
#pragma unroll
        for (int r = 0; r < 4; ++r) {
            float p = exp2f(accS[ct][r] - m_new);
            lsum += p;
            pk[r] = (_Float16)p;
        }
        *(half4_t*)&Pw[pbase + ct * 256] = pk;
    }
    lsum += __shfl_xor(lsum, 16);
    lsum += __shfl_xor(lsum, 32);
    l_run = l_run * alpha + lsum;

#pragma unroll
    for (int ct = 0; ct < 5; ++ct) O[ct] *= alpha;

#pragma unroll
    for (int ks = 0; ks < 2; ++ks) {
        half8_t pf = *(const half8_t*)&Pw[(ks * 4 + quad) * 128 + ln * 8];
#pragma unroll
        for (int ct = 0; ct < 5; ++ct) {
            half8_t vf = *(const half8_t*)&Vts[(((ks * 4 + quad) * 96) + ct * 16 + ln) * 8];
            O[ct] = __builtin_amdgcn_mfma_f32_16x16x32_f16(vf, pf, O[ct], 0, 0, 0);
        }
    }
}

// ---------------------------------------------------------------------------
// Fused dual-pass flash attention, single K/V buffer (33 KB LDS -> 4 blk/CU),
// Q fragments in registers, own pass then enc pass; latency hidden by
// inter-block wave overlap. XCD-affinity swizzle for per-head K/V L2 reuse.
// ---------------------------------------------------------------------------
__global__ __launch_bounds__(256, 4) void attn_fused(
    const _Float16* __restrict__ qh, const _Float16* __restrict__ kh,
    const _Float16* __restrict__ vth,
    const _Float16* __restrict__ ekh, const _Float16* __restrict__ evth,
    _Float16* __restrict__ xouth, float* __restrict__ loss_out)
{
    const int t = threadIdx.x;
    const int lane = t & 63;
    const int w = t >> 6;
    const int ln = lane & 15;
    const int quad = lane >> 4;

    const int lid  = blockIdx.x;             // 1024 blocks
    const int bh   = (lid & 7) * 8 + ((lid >> 3) >> 4);
    const int nblk = (lid >> 3) & 15;

    __shared__ _Float16 Ks[CHUNK_HALVES];
    __shared__ _Float16 Vs[CHUNK_HALVES];
    __shared__ _Float16 Ps[4096];   // per-wave 1024-half P^T region
    __shared__ float red[256];

    _Float16* Pw = Ps + w * 1024;

    // Q fragments straight to registers (wave-private rows)
    const _Float16* qc = qh + ((size_t)bh * 16 + nblk) * CHUNK_HALVES;
    half8_t qf[3];
#pragma unroll
    for (int ks = 0; ks < 3; ++ks)
        qf[ks] = *(const half8_t*)&qc[(((ks * 4 + quad) * 64) + w * 16 + ln) * 8];

    const _Float16* kbo = kh   + (size_t)bh * HEAD_HALVES;
    const _Float16* vbo = vth  + (size_t)bh * HEAD_HALVES;
    const _Float16* kbe = ekh  + (size_t)bh * HEAD_HALVES;
    const _Float16* vbe = evth + (size_t)bh * HEAD_HALVES;

    float4v Oo[5], Oe[5];
#pragma unroll
    for (int ct = 0; ct < 5; ++ct) {
        Oo[ct] = (float4v){0.f, 0.f, 0.f, 0.f};
        Oe[ct] = (float4v){0.f, 0.f, 0.f, 0.f};
    }
    float m_o = -1e30f, l_o = 0.f;
    float m_e = -1e30f, l_e = 0.f;

    // pass 0: own K/V
    for (int kt = 0; kt < 16; ++kt) {
        const _Float16* kc = kbo + (size_t)kt * CHUNK_HALVES;
        const _Float16* vc = vbo + (size_t)kt * CHUNK_HALVES;
        __syncthreads();
#pragma unroll
        for (int i = 0; i < 3; ++i) {
            int u = i * 256 + t;
            load16_lds(kc + u * 8, &Ks[u * 8]);
            load16_lds(vc + u * 8, &Vs[u * 8]);
        }
        __syncthreads();
        attn_step(qf, Ks, Vs, Pw, Oo, m_o, l_o, ln, quad);
    }
    // pass 1: encoder K/V
    for (int kt = 0; kt < 16; ++kt) {
        const _Float16* kc = kbe + (size_t)kt * CHUNK_HALVES;
        const _Float16* vc = vbe + (size_t)kt * CHUNK_HALVES;
        __syncthreads();
#pragma unroll
        for (int i = 0; i < 3; ++i) {
            int u = i * 256 + t;
            load16_lds(kc + u * 8, &Ks[u * 8]);
            load16_lds(vc + u * 8, &Vs[u * 8]);
        }
        __syncthreads();
        attn_step(qf, Ks, Vs, Pw, Oe, m_e, l_e, ln, quad);
    }

    const float inv_o = 1.0f / l_o;
    const float inv_e = 1.0f / l_e;

    const int b = bh >> 4, h = bh & 15;
    const int nrow = nblk * 64 + w * 16 + ln;   // this lane's Q-row

    float lacc = 0.f;
    const size_t rowbase = (size_t)(b * PN + nrow) * PC + h * PHD;
#pragma unroll
    for (int ct = 0; ct < 5; ++ct) {
        int d0 = ct * 16 + quad * 4;
        if (d0 < PHD) {                  // ct=4: only quads 0,1 valid
            half4_t oh;
#pragma unroll
            for (int r = 0; r < 4; ++r) {
                float own = Oo[ct][r] * inv_o;
                oh[r] = (_Float16)own;
                float df = own - Oe[ct][r] * inv_e;
                lacc += df * df;
            }
            *(half4_t*)&xouth[rowbase + d0] = oh;   // 8B aligned
        }
    }

    red[t] = lacc;
    __syncthreads();
    for (int off = 128; off > 0; off >>= 1) {
        if (t < off) red[t] += red[t + off];
        __syncthreads();
    }
    if (t == 0) atomicAdd(loss_out, red[0] * (1.0f / (float)OUT_ELEMS));
}

// ---------------------------------------------------------------------------
extern "C" void kernel_launch(void* const* d_in, const int* in_sizes, int n_in,
                              void* d_out, int out_size, void* d_ws, size_t ws_size,
                              hipStream_t stream)
{
    const float* x      = (const float*)d_in[0];
    const float* enc_k  = (const float*)d_in[1];
    const float* enc_v  = (const float*)d_in[2];
    const float* qkv_w  = (const float*)d_in[3];
    const float* qkv_b  = (const float*)d_in[4];
    const float* proj_w = (const float*)d_in[5];
    const float* proj_b = (const float*)d_in[6];

    float* out = (float*)d_out;

    _Float16* x_h     = (_Float16*)d_ws;
    _Float16* qkvw_h  = x_h + OUT_ELEMS;
    _Float16* projw_h = qkvw_h + (size_t)QKV_COLS * PC;
    _Float16* xout_h  = projw_h + (size_t)PC * PC;
    _Float16* q_h     = xout_h + OUT_ELEMS;
    _Float16* k_h     = q_h  + BUF_HALVES;
    _Float16* vt_h    = k_h  + BUF_HALVES;
    _Float16* ek_h    = vt_h + BUF_HALVES;
    _Float16* evt_h   = ek_h + BUF_HALVES;

    const int n8_x  = (int)(OUT_ELEMS / 8);
    const int n8_qw = QKV_COLS * PC / 8;
    const int n8_pw = PC * PC / 8;

    // 0. zero loss slot + q pads
    hipMemsetAsync(out + OUT_ELEMS, 0, sizeof(float), stream);
    zero_qpad<<<768, 256, 0, stream>>>(q_h);

    // conversions
    f32_to_f16<<<(n8_x  + 255) / 256, 256, 0, stream>>>(x,      x_h,     n8_x);
    f32_to_f16<<<(n8_qw + 255) / 256, 256, 0, stream>>>(qkv_w,  qkvw_h,  n8_qw);
    f32_to_f16<<<(n8_pw + 255) / 256, 256, 0, stream>>>(proj_w, projw_h, n8_pw);
    enc_convert<<<dim3(16, BH), 256, 0, stream>>>(enc_k, enc_v, ek_h, evt_h);

    // 1. QKV projection -> blocked f16 q/k/vt (q pre-scaled by QSCALE)
    gemm_mfma<0><<<(QKV_COLS / 128) * ((PB * PN) / 128), 256, 0, stream>>>(
        x_h, qkvw_h, qkv_b, q_h, k_h, vt_h, nullptr, QKV_COLS / 128);

    // 2. Fused own+enc attention -> xout_h + loss into out[OUT_ELEMS]
    attn_fused<<<16 * BH, 256, 0, stream>>>(
        q_h, k_h, vt_h, ek_h, evt_h, xout_h, out + OUT_ELEMS);

    // 3. Output projection (transposed, float4 stores)
    gemm_mfma<1><<<(PC / 128) * ((PB * PN) / 128), 256, 0, stream>>>(
        xout_h, projw_h, proj_b, nullptr, nullptr, nullptr, out, PC / 128);
}